// Round 1
// baseline (1017.653 us; speedup 1.0000x reference)
//
#include <hip/hip_runtime.h>
#include <math.h>

// ---------------------------------------------------------------- histogram
__global__ __launch_bounds__(256)
void hist_k(const int* __restrict__ edst, int* __restrict__ cnt, int E) {
    int t = blockIdx.x * 256 + threadIdx.x;
    if (t < E) atomicAdd(&cnt[edst[t]], 1);
}

// ---------------------------------------------------------------- scan (single block)
__global__ __launch_bounds__(1024)
void scan_k(const int* __restrict__ cnt, int* __restrict__ rowstart,
            int* __restrict__ cursor, float* __restrict__ degf, int n) {
    __shared__ int wsum[16];
    __shared__ int carry_s;
    int tid = threadIdx.x, lane = tid & 63, wid = tid >> 6;
    if (tid == 0) carry_s = 0;
    __syncthreads();
    const int CH = 4096;  // 1024 threads * 4
    for (int bse = 0; bse < n; bse += CH) {
        int idx = bse + tid * 4;
        int v[4]; int s = 0;
        for (int j = 0; j < 4; j++) { v[j] = (idx + j < n) ? cnt[idx + j] : 0; s += v[j]; }
        int x = s;
        for (int d = 1; d < 64; d <<= 1) { int y = __shfl_up(x, d); if (lane >= d) x += y; }
        if (lane == 63) wsum[wid] = x;
        __syncthreads();
        int waveoff = 0;
        for (int w = 0; w < wid; w++) waveoff += wsum[w];
        int excl = x - s + waveoff + carry_s;
        int run = excl;
        for (int j = 0; j < 4; j++) {
            int i = idx + j;
            if (i < n) {
                rowstart[i] = run; cursor[i] = run;
                degf[i] = (float)(v[j] > 0 ? v[j] : 1);
                run += v[j];
            }
        }
        __syncthreads();
        if (tid == 1023) carry_s = excl + s;
        __syncthreads();
    }
    if (tid == 0) rowstart[n] = carry_s;
}

// ---------------------------------------------------------------- scatter into CSR
__global__ __launch_bounds__(256)
void scatter_k(const int* __restrict__ esrc_in, const int* __restrict__ edst_in,
               int* __restrict__ cursor, int* __restrict__ esrc, int E) {
    int t = blockIdx.x * 256 + threadIdx.x;
    if (t < E) {
        int p = atomicAdd(&cursor[edst_in[t]], 1);
        esrc[p] = esrc_in[t];
    }
}

// ---------------------------------------------------------------- node projection pos[N,3] @ w[3,64] + b
__global__ __launch_bounds__(256)
void proj_k(const float* __restrict__ pos, const float* __restrict__ w,
            const float* __restrict__ b, float* __restrict__ X0, int n_nodes) {
    int t = blockIdx.x * 256 + threadIdx.x;
    int n = t >> 6, f = t & 63;
    if (n >= n_nodes) return;
    float p0 = pos[n * 3 + 0], p1 = pos[n * 3 + 1], p2 = pos[n * 3 + 2];
    X0[(size_t)n * 128 + f] = b[f] + p0 * w[f] + p1 * w[64 + f] + p2 * w[128 + f];
}

// ---------------------------------------------------------------- CSR mean-aggregate, one wave per node
// NC = number of 64-wide column chunks (1 -> F=64, 2 -> F=128)
template <int NC>
__global__ __launch_bounds__(256)
void agg_k(const float* __restrict__ src, int ss, int sc,
           float* __restrict__ dst, int ds_, int dc,
           const int* __restrict__ rowstart, const int* __restrict__ esrc,
           const float* __restrict__ degf, int n_nodes) {
    int wave = threadIdx.x >> 6;
    int lane = threadIdx.x & 63;
    int n = blockIdx.x * 4 + wave;
    if (n >= n_nodes) return;
    int e0 = rowstart[n], e1 = rowstart[n + 1];
    float acc0 = 0.f, acc1 = 0.f;
    for (int e = e0; e < e1; e++) {
        int s = esrc[e];
        const float* row = &src[(size_t)s * ss + sc];
        acc0 += row[lane];
        if (NC == 2) acc1 += row[64 + lane];
    }
    float inv = 1.0f / degf[n];
    dst[(size_t)n * ds_ + dc + lane] = acc0 * inv;
    if (NC == 2) dst[(size_t)n * ds_ + dc + 64 + lane] = acc1 * inv;
}

// ---------------------------------------------------------------- fused GEMM: D = act([A1|A2] @ [W1;W2] + bias)
// A: M x K gathered from up to two column-slices (k < KA1 from A1, else A2).
// W: K x FOUT, rows k < K/2 from W1, else W2 (pass W2 = W1 + (K/2)*FOUT for one matrix).
template <int K, int FOUT>
__global__ __launch_bounds__(256)
void gemm_lrelu(const float* __restrict__ A1, int a1s, int a1c, int KA1,
                const float* __restrict__ A2, int a2s, int a2c,
                const float* __restrict__ W1, const float* __restrict__ W2,
                const float* __restrict__ bias,
                float* __restrict__ D, int dstr, int dcol, int M, int doRelu) {
    const int BM = 64, BN = 64, BK = 16;
    __shared__ float As[BK][BM];
    __shared__ float Bs[BK][BN];
    int tid = threadIdx.x;
    int m0 = blockIdx.x * BM;
    int n0 = blockIdx.y * BN;
    int tx = tid & 15;   // n
    int ty = tid >> 4;   // m
    float acc[4][4] = {};
    int mA = tid >> 2;          // 0..63
    int kA = (tid & 3) * 4;     // 0,4,8,12
    int kB = tid >> 4;          // 0..15
    int nB = (tid & 15) * 4;    // 0..60
    for (int k0 = 0; k0 < K; k0 += BK) {
        // --- stage A (transposed) ---
        int kk = k0 + kA;
        const float* Ap; int Asr; int Acc;
        if (kk < KA1) { Ap = A1; Asr = a1s; Acc = a1c + kk; }
        else          { Ap = A2; Asr = a2s; Acc = a2c + (kk - KA1); }
        int gm = m0 + mA;
        float4 av;
        if (gm < M) av = *(const float4*)&Ap[(size_t)gm * Asr + Acc];
        else        av = float4{0.f, 0.f, 0.f, 0.f};
        As[kA + 0][mA] = av.x; As[kA + 1][mA] = av.y;
        As[kA + 2][mA] = av.z; As[kA + 3][mA] = av.w;
        // --- stage B ---
        int kw = k0 + kB;
        const float* Wp; int kwl;
        if (kw < K / 2) { Wp = W1; kwl = kw; } else { Wp = W2; kwl = kw - K / 2; }
        float4 bv = *(const float4*)&Wp[(size_t)kwl * FOUT + n0 + nB];
        *(float4*)&Bs[kB][nB] = bv;
        __syncthreads();
        #pragma unroll
        for (int k = 0; k < BK; k++) {
            float a[4], b[4];
            *(float4*)a = *(const float4*)&As[k][ty * 4];
            *(float4*)b = *(const float4*)&Bs[k][tx * 4];
            #pragma unroll
            for (int i = 0; i < 4; i++)
                #pragma unroll
                for (int j = 0; j < 4; j++)
                    acc[i][j] += a[i] * b[j];
        }
        __syncthreads();
    }
    #pragma unroll
    for (int i = 0; i < 4; i++) {
        int gm = m0 + ty * 4 + i;
        if (gm >= M) continue;
        #pragma unroll
        for (int j = 0; j < 4; j++) {
            int gn = n0 + tx * 4 + j;
            float v = acc[i][j] + bias[gn];
            if (doRelu) v = (v > 0.f) ? v : 0.01f * v;
            D[(size_t)gm * dstr + dcol + gn] = v;
        }
    }
}

// ---------------------------------------------------------------- pooling (batch sorted)
__global__ __launch_bounds__(256)
void pool_k(const float* __restrict__ nf, const int* __restrict__ batch,
            float* __restrict__ pooled, int n_nodes) {
    int g = blockIdx.x;
    int f = threadIdx.x;  // 0..255
    int lo = 0, hi = n_nodes;
    while (lo < hi) { int mid = (lo + hi) >> 1; if (batch[mid] < g) lo = mid + 1; else hi = mid; }
    int start = lo;
    lo = start; hi = n_nodes;
    while (lo < hi) { int mid = (lo + hi) >> 1; if (batch[mid] < g + 1) lo = mid + 1; else hi = mid; }
    int end = lo;
    float mx = -INFINITY, sm = 0.f;
    for (int i = start; i < end; i++) {
        float v = nf[(size_t)i * 256 + f];
        mx = fmaxf(mx, v);
        sm += v;
    }
    float cntf = (end > start) ? (float)(end - start) : 1.0f;
    if (end == start) mx = 0.f;  // unreachable with given inputs
    pooled[g * 512 + f] = mx;
    pooled[g * 512 + 256 + f] = sm / cntf;
}

// ---------------------------------------------------------------- launcher
extern "C" void kernel_launch(void* const* d_in, const int* in_sizes, int n_in,
                              void* d_out, int out_size, void* d_ws, size_t ws_size,
                              hipStream_t stream) {
    const float* pos   = (const float*)d_in[0];
    const int*   eidx  = (const int*)d_in[1];
    const int*   batch = (const int*)d_in[2];
    const float* w_proj = (const float*)d_in[3];
    const float* b_proj = (const float*)d_in[4];
    const float* ws0 = (const float*)d_in[5];  const float* wn0 = (const float*)d_in[6];  const float* bb0 = (const float*)d_in[7];
    const float* ws1 = (const float*)d_in[8];  const float* wn1 = (const float*)d_in[9];  const float* bb1 = (const float*)d_in[10];
    const float* ws2 = (const float*)d_in[11]; const float* wn2 = (const float*)d_in[12]; const float* bb2 = (const float*)d_in[13];
    const float* ws3 = (const float*)d_in[14]; const float* wn3 = (const float*)d_in[15]; const float* bb3 = (const float*)d_in[16];
    const float* wd1 = (const float*)d_in[17]; const float* bd1 = (const float*)d_in[18];
    const float* wd2 = (const float*)d_in[19]; const float* bd2 = (const float*)d_in[20];

    int N = in_sizes[0] / 3;
    int E = in_sizes[1] / 2;
    int G = out_size / 256;
    const int* esrc_in = eidx;
    const int* edst_in = eidx + E;

    char* base = (char*)d_ws;
    size_t off = 0;
    auto alloc = [&](size_t bytes) -> void* {
        void* p = base + off;
        off = (off + bytes + 255) & ~(size_t)255;
        return p;
    };
    int*   cnt      = (int*)alloc((size_t)(N + 1) * 4);
    int*   rowstart = (int*)alloc((size_t)(N + 1) * 4);
    int*   cursor   = (int*)alloc((size_t)N * 4);
    int*   esrc     = (int*)alloc((size_t)E * 4);
    float* degf     = (float*)alloc((size_t)N * 4);
    float* X0       = (float*)alloc((size_t)N * 128 * 4);  // [x | Sx/deg]
    float* X3       = (float*)alloc((size_t)N * 512 * 4);  // [h0,h1,h2 | Sh0,Sh1,Sh2]/deg
    float* NF       = (float*)alloc((size_t)N * 256 * 4);
    float* pooled   = (float*)alloc((size_t)G * 512 * 4);
    float* hid      = (float*)alloc((size_t)G * 512 * 4);

    // ---- CSR build ----
    hipMemsetAsync(cnt, 0, (size_t)(N + 1) * 4, stream);
    hist_k<<<(E + 255) / 256, 256, 0, stream>>>(edst_in, cnt, E);
    scan_k<<<1, 1024, 0, stream>>>(cnt, rowstart, cursor, degf, N);
    scatter_k<<<(E + 255) / 256, 256, 0, stream>>>(esrc_in, edst_in, cursor, esrc, E);

    // ---- projection ----
    proj_k<<<(N * 64 + 255) / 256, 256, 0, stream>>>(pos, w_proj, b_proj, X0, N);

    int ab = (N + 3) / 4;          // agg blocks
    int mb = (N + 63) / 64;        // gemm m-blocks

    // layer 0: X0=[x|Sx/deg] -> h0 = X3 cols 0..64
    agg_k<1><<<ab, 256, 0, stream>>>(X0, 128, 0, X0, 128, 64, rowstart, esrc, degf, N);
    gemm_lrelu<128, 64><<<dim3(mb, 1), 256, 0, stream>>>(
        X0, 128, 0, 128, X0, 128, 0, ws0, wn0, bb0, X3, 512, 0, N, 1);

    // layer 1: [h0 | Sh0/deg] -> h1 = X3 cols 64..128
    agg_k<1><<<ab, 256, 0, stream>>>(X3, 512, 0, X3, 512, 256, rowstart, esrc, degf, N);
    gemm_lrelu<128, 64><<<dim3(mb, 1), 256, 0, stream>>>(
        X3, 512, 0, 64, X3, 512, 256, ws1, wn1, bb1, X3, 512, 64, N, 1);

    // layer 2: [h1 | Sh1/deg] -> h2 = X3 cols 128..256
    agg_k<1><<<ab, 256, 0, stream>>>(X3, 512, 64, X3, 512, 320, rowstart, esrc, degf, N);
    gemm_lrelu<128, 128><<<dim3(mb, 2), 256, 0, stream>>>(
        X3, 512, 64, 64, X3, 512, 320, ws2, wn2, bb2, X3, 512, 128, N, 1);

    // layer 3: aggregate h2 (128 cols), then full K=512 GEMM -> NF
    agg_k<2><<<ab, 256, 0, stream>>>(X3, 512, 128, X3, 512, 384, rowstart, esrc, degf, N);
    gemm_lrelu<512, 256><<<dim3(mb, 4), 256, 0, stream>>>(
        X3, 512, 0, 512, X3, 512, 0, ws3, wn3, bb3, NF, 256, 0, N, 1);

    // ---- pooling ----
    pool_k<<<G, 256, 0, stream>>>(NF, batch, pooled, N);

    // ---- dense head ----
    gemm_lrelu<512, 512><<<dim3((G + 63) / 64, 8), 256, 0, stream>>>(
        pooled, 512, 0, 512, pooled, 512, 0, wd1, wd1 + 256 * 512, bd1, hid, 512, 0, G, 1);
    gemm_lrelu<512, 256><<<dim3((G + 63) / 64, 4), 256, 0, stream>>>(
        hid, 512, 0, 512, hid, 512, 0, wd2, wd2 + 256 * 256, bd2, (float*)d_out, 256, 0, G, 0);
}

// Round 2
// 710.224 us; speedup vs baseline: 1.4329x; 1.4329x over previous
//
#include <hip/hip_runtime.h>
#include <math.h>

typedef short s16x8 __attribute__((ext_vector_type(8)));
typedef unsigned short us8 __attribute__((ext_vector_type(8)));
typedef float f32x4 __attribute__((ext_vector_type(4)));

__device__ inline unsigned short f2bf(float f) {
    unsigned int u = __float_as_uint(f);
    u += 0x7fffu + ((u >> 16) & 1u);   // round-to-nearest-even
    return (unsigned short)(u >> 16);
}

// ---------------------------------------------------------------- histogram
__global__ __launch_bounds__(256)
void hist_k(const int* __restrict__ edst, int* __restrict__ cnt, int E) {
    int t = blockIdx.x * 256 + threadIdx.x;
    if (t < E) atomicAdd(&cnt[edst[t]], 1);
}

// ---------------------------------------------------------------- scan (single block)
__global__ __launch_bounds__(1024)
void scan_k(const int* __restrict__ cnt, int* __restrict__ rowstart,
            int* __restrict__ cursor, float* __restrict__ degf, int n) {
    __shared__ int wsum[16];
    __shared__ int carry_s;
    int tid = threadIdx.x, lane = tid & 63, wid = tid >> 6;
    if (tid == 0) carry_s = 0;
    __syncthreads();
    const int CH = 4096;  // 1024 threads * 4
    for (int bse = 0; bse < n; bse += CH) {
        int idx = bse + tid * 4;
        int v[4]; int s = 0;
        for (int j = 0; j < 4; j++) { v[j] = (idx + j < n) ? cnt[idx + j] : 0; s += v[j]; }
        int x = s;
        for (int d = 1; d < 64; d <<= 1) { int y = __shfl_up(x, d); if (lane >= d) x += y; }
        if (lane == 63) wsum[wid] = x;
        __syncthreads();
        int waveoff = 0;
        for (int w = 0; w < wid; w++) waveoff += wsum[w];
        int excl = x - s + waveoff + carry_s;
        int run = excl;
        for (int j = 0; j < 4; j++) {
            int i = idx + j;
            if (i < n) {
                rowstart[i] = run; cursor[i] = run;
                degf[i] = (float)(v[j] > 0 ? v[j] : 1);
                run += v[j];
            }
        }
        __syncthreads();
        if (tid == 1023) carry_s = excl + s;
        __syncthreads();
    }
    if (tid == 0) rowstart[n] = carry_s;
}

// ---------------------------------------------------------------- scatter into CSR
__global__ __launch_bounds__(256)
void scatter_k(const int* __restrict__ esrc_in, const int* __restrict__ edst_in,
               int* __restrict__ cursor, int* __restrict__ esrc, int E) {
    int t = blockIdx.x * 256 + threadIdx.x;
    if (t < E) {
        int p = atomicAdd(&cursor[edst_in[t]], 1);
        esrc[p] = esrc_in[t];
    }
}

// ---------------------------------------------------------------- node projection pos[N,3] @ w[3,64] + b
__global__ __launch_bounds__(256)
void proj_k(const float* __restrict__ pos, const float* __restrict__ w,
            const float* __restrict__ b, float* __restrict__ X0, int n_nodes) {
    int t = blockIdx.x * 256 + threadIdx.x;
    int n = t >> 6, f = t & 63;
    if (n >= n_nodes) return;
    float p0 = pos[n * 3 + 0], p1 = pos[n * 3 + 1], p2 = pos[n * 3 + 2];
    X0[(size_t)n * 128 + f] = b[f] + p0 * w[f] + p1 * w[64 + f] + p2 * w[128 + f];
}

// ---------------------------------------------------------------- CSR mean-aggregate, one wave per node
template <int NC>
__global__ __launch_bounds__(256)
void agg_k(const float* __restrict__ src, int ss, int sc,
           float* __restrict__ dst, int ds_, int dc,
           const int* __restrict__ rowstart, const int* __restrict__ esrc,
           const float* __restrict__ degf, int n_nodes) {
    int wave = threadIdx.x >> 6;
    int lane = threadIdx.x & 63;
    int n = blockIdx.x * 4 + wave;
    if (n >= n_nodes) return;
    int e0 = rowstart[n], e1 = rowstart[n + 1];
    float acc0 = 0.f, acc1 = 0.f;
    for (int e = e0; e < e1; e++) {
        int s = esrc[e];
        const float* row = &src[(size_t)s * ss + sc];
        acc0 += row[lane];
        if (NC == 2) acc1 += row[64 + lane];
    }
    float inv = 1.0f / degf[n];
    dst[(size_t)n * ds_ + dc + lane] = acc0 * inv;
    if (NC == 2) dst[(size_t)n * ds_ + dc + 64 + lane] = acc1 * inv;
}

// ---------------------------------------------------------------- fp32 fused GEMM (small layers + head)
template <int K, int FOUT>
__global__ __launch_bounds__(256)
void gemm_lrelu(const float* __restrict__ A1, int a1s, int a1c, int KA1,
                const float* __restrict__ A2, int a2s, int a2c,
                const float* __restrict__ W1, const float* __restrict__ W2,
                const float* __restrict__ bias,
                float* __restrict__ D, int dstr, int dcol, int M, int doRelu) {
    const int BM = 64, BN = 64, BK = 16;
    __shared__ float As[BK][BM];
    __shared__ float Bs[BK][BN];
    int tid = threadIdx.x;
    int m0 = blockIdx.x * BM;
    int n0 = blockIdx.y * BN;
    int tx = tid & 15;
    int ty = tid >> 4;
    float acc[4][4] = {};
    int mA = tid >> 2;
    int kA = (tid & 3) * 4;
    int kB = tid >> 4;
    int nB = (tid & 15) * 4;
    for (int k0 = 0; k0 < K; k0 += BK) {
        int kk = k0 + kA;
        const float* Ap; int Asr; int Acc;
        if (kk < KA1) { Ap = A1; Asr = a1s; Acc = a1c + kk; }
        else          { Ap = A2; Asr = a2s; Acc = a2c + (kk - KA1); }
        int gm = m0 + mA;
        float4 av;
        if (gm < M) av = *(const float4*)&Ap[(size_t)gm * Asr + Acc];
        else        av = float4{0.f, 0.f, 0.f, 0.f};
        As[kA + 0][mA] = av.x; As[kA + 1][mA] = av.y;
        As[kA + 2][mA] = av.z; As[kA + 3][mA] = av.w;
        int kw = k0 + kB;
        const float* Wp; int kwl;
        if (kw < K / 2) { Wp = W1; kwl = kw; } else { Wp = W2; kwl = kw - K / 2; }
        float4 bv = *(const float4*)&Wp[(size_t)kwl * FOUT + n0 + nB];
        *(float4*)&Bs[kB][nB] = bv;
        __syncthreads();
        #pragma unroll
        for (int k = 0; k < BK; k++) {
            float a[4], b[4];
            *(float4*)a = *(const float4*)&As[k][ty * 4];
            *(float4*)b = *(const float4*)&Bs[k][tx * 4];
            #pragma unroll
            for (int i = 0; i < 4; i++)
                #pragma unroll
                for (int j = 0; j < 4; j++)
                    acc[i][j] += a[i] * b[j];
        }
        __syncthreads();
    }
    #pragma unroll
    for (int i = 0; i < 4; i++) {
        int gm = m0 + ty * 4 + i;
        if (gm >= M) continue;
        #pragma unroll
        for (int j = 0; j < 4; j++) {
            int gn = n0 + tx * 4 + j;
            float v = acc[i][j] + bias[gn];
            if (doRelu) v = (v > 0.f) ? v : 0.01f * v;
            D[(size_t)gm * dstr + dcol + gn] = v;
        }
    }
}

// ---------------------------------------------------------------- bf16 MFMA GEMM: D = lrelu(A @ [W1;W2] + b)
// A fp32 [M x K] stride astr; W rows k<K/2 from W1, else W2 (each (K/2) x FOUT fp32).
// Block: 256 thr (4 waves), tile BM=64, BN=64, BK=32. LDS bf16, row pad 72 halves (144B).
template <int K, int FOUT>
__global__ __launch_bounds__(256)
void gemm_mfma(const float* __restrict__ A, int astr,
               const float* __restrict__ W1, const float* __restrict__ W2,
               const float* __restrict__ bias,
               float* __restrict__ D, int dstr, int M, int doRelu) {
    const int LD = 72;  // halves per LDS row (144 B -> bank-start stride 4 -> 2-way, free)
    __shared__ unsigned short As[64 * LD];
    __shared__ unsigned short Bs[64 * LD];
    int t = threadIdx.x;
    int w = t >> 6, lane = t & 63;
    int lm = lane & 15, kb = lane >> 4;
    int m0 = blockIdx.x * 64;
    int n0 = blockIdx.y * 64;

    // staging coords
    int arow = t >> 2;            // 0..63
    int akq  = (t & 3) * 8;       // 0,8,16,24
    int bn   = t & 63;            // 0..63
    int bkq  = (t >> 6) * 8;      // 0,8,16,24

    f32x4 acc[4] = {};

    for (int k0 = 0; k0 < K; k0 += 32) {
        // ---- stage A: 64 rows x 32 k, fp32 -> bf16 ----
        {
            int gm = m0 + arow;
            float4 v0, v1;
            if (gm < M) {
                const float* p = &A[(size_t)gm * astr + k0 + akq];
                v0 = *(const float4*)p;
                v1 = *(const float4*)(p + 4);
            } else {
                v0 = float4{0.f,0.f,0.f,0.f}; v1 = v0;
            }
            us8 pk;
            pk[0]=f2bf(v0.x); pk[1]=f2bf(v0.y); pk[2]=f2bf(v0.z); pk[3]=f2bf(v0.w);
            pk[4]=f2bf(v1.x); pk[5]=f2bf(v1.y); pk[6]=f2bf(v1.z); pk[7]=f2bf(v1.w);
            *(us8*)&As[arow * LD + akq] = pk;
        }
        // ---- stage B transposed: Bs[n][kk] = W[k0+kk][n0+n] ----
        {
            float vb[8];
            #pragma unroll
            for (int j = 0; j < 8; j++) {
                int kw = k0 + bkq + j;
                const float* Wp; int kwl;
                if (kw < K / 2) { Wp = W1; kwl = kw; } else { Wp = W2; kwl = kw - K / 2; }
                vb[j] = Wp[(size_t)kwl * FOUT + n0 + bn];
            }
            us8 pk;
            #pragma unroll
            for (int j = 0; j < 8; j++) pk[j] = f2bf(vb[j]);
            *(us8*)&Bs[bn * LD + bkq] = pk;
        }
        __syncthreads();
        // ---- 4 MFMAs per wave ----
        s16x8 a = *(const s16x8*)&As[(w * 16 + lm) * LD + kb * 8];
        #pragma unroll
        for (int nt = 0; nt < 4; nt++) {
            s16x8 b = *(const s16x8*)&Bs[(nt * 16 + lm) * LD + kb * 8];
            acc[nt] = __builtin_amdgcn_mfma_f32_16x16x32_bf16(a, b, acc[nt], 0, 0, 0);
        }
        __syncthreads();
    }

    // ---- epilogue: C/D map col=lane&15, row=(lane>>4)*4+reg ----
    #pragma unroll
    for (int nt = 0; nt < 4; nt++) {
        int gn = n0 + nt * 16 + lm;
        float bv = bias[gn];
        #pragma unroll
        for (int r = 0; r < 4; r++) {
            int gm = m0 + w * 16 + kb * 4 + r;
            if (gm >= M) continue;
            float v = acc[nt][r] + bv;
            if (doRelu) v = (v > 0.f) ? v : 0.01f * v;
            D[(size_t)gm * dstr + gn] = v;
        }
    }
}

// ---------------------------------------------------------------- pooling, stage 0: init
__global__ __launch_bounds__(256)
void pool_init(float* __restrict__ pmax, float* __restrict__ psum,
               int* __restrict__ gcnt, int G) {
    int t = blockIdx.x * 256 + threadIdx.x;
    if (t < G * 256) { pmax[t] = -INFINITY; psum[t] = 0.f; }
    if (t < G) gcnt[t] = 0;
}

__device__ inline void atomicMaxFloat(float* addr, float v) {
    if (v >= 0.f) atomicMax((int*)addr, __float_as_int(v));
    else          atomicMin((unsigned int*)addr, __float_as_uint(v));
}

// ---------------------------------------------------------------- pooling, stage 1: chunked partials
#define PCHUNK 128
__global__ __launch_bounds__(256)
void pool_partial(const float* __restrict__ nf, const int* __restrict__ batch,
                  float* __restrict__ pmax, float* __restrict__ psum,
                  int* __restrict__ gcnt, int n_nodes) {
    __shared__ int bsh[PCHUNK];
    int c0 = blockIdx.x * PCHUNK;
    int c1 = min(c0 + PCHUNK, n_nodes);
    int f = threadIdx.x;
    for (int i = c0 + f; i < c1; i += 256) bsh[i - c0] = batch[i];
    __syncthreads();
    float mx = -INFINITY, sm = 0.f;
    int cur = bsh[0], segstart = c0;
    for (int i = c0; i < c1; i++) {
        int g = bsh[i - c0];
        if (g != cur) {
            atomicMaxFloat(&pmax[cur * 256 + f], mx);
            atomicAdd(&psum[cur * 256 + f], sm);
            if (f == 0) atomicAdd(&gcnt[cur], i - segstart);
            mx = -INFINITY; sm = 0.f; cur = g; segstart = i;
        }
        float v = nf[(size_t)i * 256 + f];
        mx = fmaxf(mx, v);
        sm += v;
    }
    atomicMaxFloat(&pmax[cur * 256 + f], mx);
    atomicAdd(&psum[cur * 256 + f], sm);
    if (f == 0) atomicAdd(&gcnt[cur], c1 - segstart);
}

// ---------------------------------------------------------------- pooling, stage 2: finalize
__global__ __launch_bounds__(256)
void pool_final(const float* __restrict__ pmax, const float* __restrict__ psum,
                const int* __restrict__ gcnt, float* __restrict__ pooled, int G) {
    int t = blockIdx.x * 256 + threadIdx.x;
    if (t >= G * 256) return;
    int g = t >> 8, f = t & 255;
    int c = gcnt[g];
    float mx = pmax[t];
    if (c == 0) mx = 0.f;
    pooled[g * 512 + f] = mx;
    pooled[g * 512 + 256 + f] = psum[t] / (float)(c > 0 ? c : 1);
}

// ---------------------------------------------------------------- launcher
extern "C" void kernel_launch(void* const* d_in, const int* in_sizes, int n_in,
                              void* d_out, int out_size, void* d_ws, size_t ws_size,
                              hipStream_t stream) {
    const float* pos   = (const float*)d_in[0];
    const int*   eidx  = (const int*)d_in[1];
    const int*   batch = (const int*)d_in[2];
    const float* w_proj = (const float*)d_in[3];
    const float* b_proj = (const float*)d_in[4];
    const float* ws0 = (const float*)d_in[5];  const float* wn0 = (const float*)d_in[6];  const float* bb0 = (const float*)d_in[7];
    const float* ws1 = (const float*)d_in[8];  const float* wn1 = (const float*)d_in[9];  const float* bb1 = (const float*)d_in[10];
    const float* ws2 = (const float*)d_in[11]; const float* wn2 = (const float*)d_in[12]; const float* bb2 = (const float*)d_in[13];
    const float* ws3 = (const float*)d_in[14]; const float* wn3 = (const float*)d_in[15]; const float* bb3 = (const float*)d_in[16];
    const float* wd1 = (const float*)d_in[17]; const float* bd1 = (const float*)d_in[18];
    const float* wd2 = (const float*)d_in[19]; const float* bd2 = (const float*)d_in[20];

    int N = in_sizes[0] / 3;
    int E = in_sizes[1] / 2;
    int G = out_size / 256;
    const int* esrc_in = eidx;
    const int* edst_in = eidx + E;

    char* base = (char*)d_ws;
    size_t off = 0;
    auto alloc = [&](size_t bytes) -> void* {
        void* p = base + off;
        off = (off + bytes + 255) & ~(size_t)255;
        return p;
    };
    int*   cnt      = (int*)alloc((size_t)(N + 1) * 4);
    int*   rowstart = (int*)alloc((size_t)(N + 1) * 4);
    int*   cursor   = (int*)alloc((size_t)N * 4);
    int*   esrc     = (int*)alloc((size_t)E * 4);
    float* degf     = (float*)alloc((size_t)N * 4);
    float* X0       = (float*)alloc((size_t)N * 128 * 4);  // [x | Sx/deg]
    float* X3       = (float*)alloc((size_t)N * 512 * 4);  // [h0,h1,h2 | Sh0,Sh1,Sh2]/deg
    float* NF       = (float*)alloc((size_t)N * 256 * 4);
    float* pooled   = (float*)alloc((size_t)G * 512 * 4);
    float* hid      = (float*)alloc((size_t)G * 512 * 4);
    float* pmax     = (float*)alloc((size_t)G * 256 * 4);
    float* psum     = (float*)alloc((size_t)G * 256 * 4);
    int*   gcnt     = (int*)alloc((size_t)G * 4);

    // ---- CSR build ----
    hipMemsetAsync(cnt, 0, (size_t)(N + 1) * 4, stream);
    hist_k<<<(E + 255) / 256, 256, 0, stream>>>(edst_in, cnt, E);
    scan_k<<<1, 1024, 0, stream>>>(cnt, rowstart, cursor, degf, N);
    scatter_k<<<(E + 255) / 256, 256, 0, stream>>>(esrc_in, edst_in, cursor, esrc, E);

    // ---- projection ----
    proj_k<<<(N * 64 + 255) / 256, 256, 0, stream>>>(pos, w_proj, b_proj, X0, N);

    int ab = (N + 3) / 4;
    int mb = (N + 63) / 64;

    // layer 0
    agg_k<1><<<ab, 256, 0, stream>>>(X0, 128, 0, X0, 128, 64, rowstart, esrc, degf, N);
    gemm_lrelu<128, 64><<<dim3(mb, 1), 256, 0, stream>>>(
        X0, 128, 0, 128, X0, 128, 0, ws0, wn0, bb0, X3, 512, 0, N, 1);

    // layer 1
    agg_k<1><<<ab, 256, 0, stream>>>(X3, 512, 0, X3, 512, 256, rowstart, esrc, degf, N);
    gemm_lrelu<128, 64><<<dim3(mb, 1), 256, 0, stream>>>(
        X3, 512, 0, 64, X3, 512, 256, ws1, wn1, bb1, X3, 512, 64, N, 1);

    // layer 2
    agg_k<1><<<ab, 256, 0, stream>>>(X3, 512, 64, X3, 512, 320, rowstart, esrc, degf, N);
    gemm_lrelu<128, 128><<<dim3(mb, 2), 256, 0, stream>>>(
        X3, 512, 64, 64, X3, 512, 320, ws2, wn2, bb2, X3, 512, 128, N, 1);

    // layer 3: aggregate h2, then K=512 MFMA GEMM -> NF
    agg_k<2><<<ab, 256, 0, stream>>>(X3, 512, 128, X3, 512, 384, rowstart, esrc, degf, N);
    gemm_mfma<512, 256><<<dim3(mb, 4), 256, 0, stream>>>(
        X3, 512, ws3, wn3, bb3, NF, 256, N, 1);

    // ---- pooling (two-stage, parallel) ----
    pool_init<<<(G * 256 + 255) / 256, 256, 0, stream>>>(pmax, psum, gcnt, G);
    pool_partial<<<(N + PCHUNK - 1) / PCHUNK, 256, 0, stream>>>(NF, batch, pmax, psum, gcnt, N);
    pool_final<<<(G * 256 + 255) / 256, 256, 0, stream>>>(pmax, psum, gcnt, pooled, G);

    // ---- dense head ----
    gemm_lrelu<512, 512><<<dim3((G + 63) / 64, 8), 256, 0, stream>>>(
        pooled, 512, 0, 512, pooled, 512, 0, wd1, wd1 + 256 * 512, bd1, hid, 512, 0, G, 1);
    gemm_lrelu<512, 256><<<dim3((G + 63) / 64, 4), 256, 0, stream>>>(
        hid, 512, 0, 512, hid, 512, 0, wd2, wd2 + 256 * 256, bd2, (float*)d_out, 256, 0, G, 0);
}

// Round 3
// 671.286 us; speedup vs baseline: 1.5160x; 1.0580x over previous
//
#include <hip/hip_runtime.h>
#include <math.h>

typedef short s16x8 __attribute__((ext_vector_type(8)));
typedef unsigned short us8 __attribute__((ext_vector_type(8)));
typedef float f32x4 __attribute__((ext_vector_type(4)));

__device__ inline unsigned short f2bf(float f) {
    unsigned int u = __float_as_uint(f);
    u += 0x7fffu + ((u >> 16) & 1u);   // round-to-nearest-even
    return (unsigned short)(u >> 16);
}
__device__ inline float bf2f(unsigned short h) {
    return __uint_as_float(((unsigned int)h) << 16);
}

// ---------------------------------------------------------------- histogram
__global__ __launch_bounds__(256)
void hist_k(const int* __restrict__ edst, int* __restrict__ cnt, int E) {
    int t = blockIdx.x * 256 + threadIdx.x;
    if (t < E) atomicAdd(&cnt[edst[t]], 1);
}

// ---------------------------------------------------------------- parallel scan (3 stages)
#define SCHUNK 1024
__global__ __launch_bounds__(256)
void scan_part(const int* __restrict__ cnt, int* __restrict__ rowstart,
               int* __restrict__ psum, int n) {
    __shared__ int wsum[4];
    int b = blockIdx.x;
    int base = b * SCHUNK;
    int tid = threadIdx.x, lane = tid & 63, wid = tid >> 6;
    int idx = base + tid * 4;
    int v[4]; int s = 0;
    #pragma unroll
    for (int j = 0; j < 4; j++) { v[j] = (idx + j < n) ? cnt[idx + j] : 0; s += v[j]; }
    int x = s;
    for (int d = 1; d < 64; d <<= 1) { int y = __shfl_up(x, d); if (lane >= d) x += y; }
    if (lane == 63) wsum[wid] = x;
    __syncthreads();
    int off = 0;
    for (int w = 0; w < wid; w++) off += wsum[w];
    int excl = x - s + off;
    int run = excl;
    #pragma unroll
    for (int j = 0; j < 4; j++) {
        if (idx + j < n) rowstart[idx + j] = run;
        run += v[j];
    }
    if (tid == 255) psum[b] = off + x;   // block total
}

__global__ __launch_bounds__(64)
void scan_tops(int* __restrict__ psum, int* __restrict__ rowstart, int PB, int n) {
    int lane = threadIdx.x;
    int v = (lane < PB) ? psum[lane] : 0;
    int x = v;
    for (int d = 1; d < 64; d <<= 1) { int y = __shfl_up(x, d); if (lane >= d) x += y; }
    if (lane < PB) psum[lane] = x - v;      // exclusive base per chunk
    if (lane == 63) rowstart[n] = x;        // grand total (E)
}

__global__ __launch_bounds__(256)
void scan_fix(const int* __restrict__ cnt, int* __restrict__ rowstart,
              const int* __restrict__ psum, int* __restrict__ cursor,
              float* __restrict__ degf, int n) {
    int b = blockIdx.x;
    int base = b * SCHUNK;
    int tid = threadIdx.x;
    int add = psum[b];
    #pragma unroll
    for (int k = 0; k < 4; k++) {
        int i = base + k * 256 + tid;
        if (i < n) {
            int r = rowstart[i] + add;
            rowstart[i] = r; cursor[i] = r;
            int c = cnt[i];
            degf[i] = (float)(c > 0 ? c : 1);
        }
    }
}

// ---------------------------------------------------------------- scatter into CSR
__global__ __launch_bounds__(256)
void scatter_k(const int* __restrict__ esrc_in, const int* __restrict__ edst_in,
               int* __restrict__ cursor, int* __restrict__ esrc, int E) {
    int t = blockIdx.x * 256 + threadIdx.x;
    if (t < E) {
        int p = atomicAdd(&cursor[edst_in[t]], 1);
        esrc[p] = esrc_in[t];
    }
}

// ---------------------------------------------------------------- node projection pos[N,3] @ w[3,64] + b
__global__ __launch_bounds__(256)
void proj_k(const float* __restrict__ pos, const float* __restrict__ w,
            const float* __restrict__ b, float* __restrict__ X0,
            unsigned short* __restrict__ xb, int n_nodes) {
    int t = blockIdx.x * 256 + threadIdx.x;
    int n = t >> 6, f = t & 63;
    if (n >= n_nodes) return;
    float p0 = pos[n * 3 + 0], p1 = pos[n * 3 + 1], p2 = pos[n * 3 + 2];
    float v = b[f] + p0 * w[f] + p1 * w[64 + f] + p2 * w[128 + f];
    X0[(size_t)n * 128 + f] = v;
    xb[(size_t)n * 64 + f] = f2bf(v);
}

// ---------------------------------------------------------------- CSR mean-aggregate from compact bf16 mirror
// F = feature width of mirror (64 or 128). One wave per node. fp32 accumulate.
template <int F>
__global__ __launch_bounds__(256)
void agg_bf(const unsigned short* __restrict__ src,
            float* __restrict__ dst, int ds_, int dc,
            const int* __restrict__ rowstart, const int* __restrict__ esrc,
            const float* __restrict__ degf, int n_nodes) {
    int wave = threadIdx.x >> 6;
    int lane = threadIdx.x & 63;
    int n = blockIdx.x * 4 + wave;
    if (n >= n_nodes) return;
    int e0 = rowstart[n], e1 = rowstart[n + 1];
    float acc0 = 0.f, acc1 = 0.f;
    for (int e = e0; e < e1; e++) {
        int s = esrc[e];
        if (F == 64) {
            acc0 += bf2f(src[(size_t)s * 64 + lane]);
        } else {
            unsigned int pr = *(const unsigned int*)&src[(size_t)s * 128 + 2 * lane];
            acc0 += bf2f((unsigned short)(pr & 0xffffu));
            acc1 += bf2f((unsigned short)(pr >> 16));
        }
    }
    float inv = 1.0f / degf[n];
    if (F == 64) {
        dst[(size_t)n * ds_ + dc + lane] = acc0 * inv;
    } else {
        float2 o; o.x = acc0 * inv; o.y = acc1 * inv;
        *(float2*)&dst[(size_t)n * ds_ + dc + 2 * lane] = o;
    }
}

// ---------------------------------------------------------------- fp32 fused GEMM (layers 0-2 + head)
// optional compact bf16 mirror output (stride FOUT), pass nullptr to skip
template <int K, int FOUT>
__global__ __launch_bounds__(256)
void gemm_lrelu(const float* __restrict__ A1, int a1s, int a1c, int KA1,
                const float* __restrict__ A2, int a2s, int a2c,
                const float* __restrict__ W1, const float* __restrict__ W2,
                const float* __restrict__ bias,
                float* __restrict__ D, int dstr, int dcol,
                unsigned short* __restrict__ Mir, int M, int doRelu) {
    const int BM = 64, BN = 64, BK = 16;
    __shared__ float As[BK][BM];
    __shared__ float Bs[BK][BN];
    int tid = threadIdx.x;
    int m0 = blockIdx.x * BM;
    int n0 = blockIdx.y * BN;
    int tx = tid & 15;
    int ty = tid >> 4;
    float acc[4][4] = {};
    int mA = tid >> 2;
    int kA = (tid & 3) * 4;
    int kB = tid >> 4;
    int nB = (tid & 15) * 4;
    for (int k0 = 0; k0 < K; k0 += BK) {
        int kk = k0 + kA;
        const float* Ap; int Asr; int Acc;
        if (kk < KA1) { Ap = A1; Asr = a1s; Acc = a1c + kk; }
        else          { Ap = A2; Asr = a2s; Acc = a2c + (kk - KA1); }
        int gm = m0 + mA;
        float4 av;
        if (gm < M) av = *(const float4*)&Ap[(size_t)gm * Asr + Acc];
        else        av = float4{0.f, 0.f, 0.f, 0.f};
        As[kA + 0][mA] = av.x; As[kA + 1][mA] = av.y;
        As[kA + 2][mA] = av.z; As[kA + 3][mA] = av.w;
        int kw = k0 + kB;
        const float* Wp; int kwl;
        if (kw < K / 2) { Wp = W1; kwl = kw; } else { Wp = W2; kwl = kw - K / 2; }
        float4 bv = *(const float4*)&Wp[(size_t)kwl * FOUT + n0 + nB];
        *(float4*)&Bs[kB][nB] = bv;
        __syncthreads();
        #pragma unroll
        for (int k = 0; k < BK; k++) {
            float a[4], b[4];
            *(float4*)a = *(const float4*)&As[k][ty * 4];
            *(float4*)b = *(const float4*)&Bs[k][tx * 4];
            #pragma unroll
            for (int i = 0; i < 4; i++)
                #pragma unroll
                for (int j = 0; j < 4; j++)
                    acc[i][j] += a[i] * b[j];
        }
        __syncthreads();
    }
    #pragma unroll
    for (int i = 0; i < 4; i++) {
        int gm = m0 + ty * 4 + i;
        if (gm >= M) continue;
        #pragma unroll
        for (int j = 0; j < 4; j++) {
            int gn = n0 + tx * 4 + j;
            float v = acc[i][j] + bias[gn];
            if (doRelu) v = (v > 0.f) ? v : 0.01f * v;
            D[(size_t)gm * dstr + dcol + gn] = v;
            if (Mir) Mir[(size_t)gm * FOUT + gn] = f2bf(v);
        }
    }
}

// ---------------------------------------------------------------- bf16 MFMA GEMM (layer 3): D = lrelu(A @ [W1;W2] + b)
template <int K, int FOUT>
__global__ __launch_bounds__(256)
void gemm_mfma(const float* __restrict__ A, int astr,
               const float* __restrict__ W1, const float* __restrict__ W2,
               const float* __restrict__ bias,
               float* __restrict__ D, int dstr, int M, int doRelu) {
    const int LD = 72;  // halves per LDS row (144 B -> bank-start stride 4 -> 2-way, free)
    __shared__ unsigned short As[64 * LD];
    __shared__ unsigned short Bs[64 * LD];
    int t = threadIdx.x;
    int w = t >> 6, lane = t & 63;
    int lm = lane & 15, kb = lane >> 4;
    int m0 = blockIdx.x * 64;
    int n0 = blockIdx.y * 64;

    int arow = t >> 2;
    int akq  = (t & 3) * 8;
    int bn   = t & 63;
    int bkq  = (t >> 6) * 8;

    f32x4 acc[4] = {};

    for (int k0 = 0; k0 < K; k0 += 32) {
        {
            int gm = m0 + arow;
            float4 v0, v1;
            if (gm < M) {
                const float* p = &A[(size_t)gm * astr + k0 + akq];
                v0 = *(const float4*)p;
                v1 = *(const float4*)(p + 4);
            } else {
                v0 = float4{0.f,0.f,0.f,0.f}; v1 = v0;
            }
            us8 pk;
            pk[0]=f2bf(v0.x); pk[1]=f2bf(v0.y); pk[2]=f2bf(v0.z); pk[3]=f2bf(v0.w);
            pk[4]=f2bf(v1.x); pk[5]=f2bf(v1.y); pk[6]=f2bf(v1.z); pk[7]=f2bf(v1.w);
            *(us8*)&As[arow * LD + akq] = pk;
        }
        {
            float vb[8];
            #pragma unroll
            for (int j = 0; j < 8; j++) {
                int kw = k0 + bkq + j;
                const float* Wp; int kwl;
                if (kw < K / 2) { Wp = W1; kwl = kw; } else { Wp = W2; kwl = kw - K / 2; }
                vb[j] = Wp[(size_t)kwl * FOUT + n0 + bn];
            }
            us8 pk;
            #pragma unroll
            for (int j = 0; j < 8; j++) pk[j] = f2bf(vb[j]);
            *(us8*)&Bs[bn * LD + bkq] = pk;
        }
        __syncthreads();
        s16x8 a = *(const s16x8*)&As[(w * 16 + lm) * LD + kb * 8];
        #pragma unroll
        for (int nt = 0; nt < 4; nt++) {
            s16x8 b = *(const s16x8*)&Bs[(nt * 16 + lm) * LD + kb * 8];
            acc[nt] = __builtin_amdgcn_mfma_f32_16x16x32_bf16(a, b, acc[nt], 0, 0, 0);
        }
        __syncthreads();
    }

    #pragma unroll
    for (int nt = 0; nt < 4; nt++) {
        int gn = n0 + nt * 16 + lm;
        float bv = bias[gn];
        #pragma unroll
        for (int r = 0; r < 4; r++) {
            int gm = m0 + w * 16 + kb * 4 + r;
            if (gm >= M) continue;
            float v = acc[nt][r] + bv;
            if (doRelu) v = (v > 0.f) ? v : 0.01f * v;
            D[(size_t)gm * dstr + gn] = v;
        }
    }
}

// ---------------------------------------------------------------- pooling
__global__ __launch_bounds__(256)
void pool_init(float* __restrict__ pmax, float* __restrict__ psum,
               int* __restrict__ gcnt, int G) {
    int t = blockIdx.x * 256 + threadIdx.x;
    if (t < G * 256) { pmax[t] = -INFINITY; psum[t] = 0.f; }
    if (t < G) gcnt[t] = 0;
}

__device__ inline void atomicMaxFloat(float* addr, float v) {
    if (v >= 0.f) atomicMax((int*)addr, __float_as_int(v));
    else          atomicMin((unsigned int*)addr, __float_as_uint(v));
}

#define PCHUNK 128
__global__ __launch_bounds__(256)
void pool_partial(const float* __restrict__ nf, const int* __restrict__ batch,
                  float* __restrict__ pmax, float* __restrict__ psum,
                  int* __restrict__ gcnt, int n_nodes) {
    __shared__ int bsh[PCHUNK];
    int c0 = blockIdx.x * PCHUNK;
    int c1 = min(c0 + PCHUNK, n_nodes);
    int f = threadIdx.x;
    for (int i = c0 + f; i < c1; i += 256) bsh[i - c0] = batch[i];
    __syncthreads();
    float mx = -INFINITY, sm = 0.f;
    int cur = bsh[0], segstart = c0;
    for (int i = c0; i < c1; i++) {
        int g = bsh[i - c0];
        if (g != cur) {
            atomicMaxFloat(&pmax[cur * 256 + f], mx);
            atomicAdd(&psum[cur * 256 + f], sm);
            if (f == 0) atomicAdd(&gcnt[cur], i - segstart);
            mx = -INFINITY; sm = 0.f; cur = g; segstart = i;
        }
        float v = nf[(size_t)i * 256 + f];
        mx = fmaxf(mx, v);
        sm += v;
    }
    atomicMaxFloat(&pmax[cur * 256 + f], mx);
    atomicAdd(&psum[cur * 256 + f], sm);
    if (f == 0) atomicAdd(&gcnt[cur], c1 - segstart);
}

__global__ __launch_bounds__(256)
void pool_final(const float* __restrict__ pmax, const float* __restrict__ psum,
                const int* __restrict__ gcnt, float* __restrict__ pooled, int G) {
    int t = blockIdx.x * 256 + threadIdx.x;
    if (t >= G * 256) return;
    int g = t >> 8, f = t & 255;
    int c = gcnt[g];
    float mx = pmax[t];
    if (c == 0) mx = 0.f;
    pooled[g * 512 + f] = mx;
    pooled[g * 512 + 256 + f] = psum[t] / (float)(c > 0 ? c : 1);
}

// ---------------------------------------------------------------- launcher
extern "C" void kernel_launch(void* const* d_in, const int* in_sizes, int n_in,
                              void* d_out, int out_size, void* d_ws, size_t ws_size,
                              hipStream_t stream) {
    const float* pos   = (const float*)d_in[0];
    const int*   eidx  = (const int*)d_in[1];
    const int*   batch = (const int*)d_in[2];
    const float* w_proj = (const float*)d_in[3];
    const float* b_proj = (const float*)d_in[4];
    const float* ws0 = (const float*)d_in[5];  const float* wn0 = (const float*)d_in[6];  const float* bb0 = (const float*)d_in[7];
    const float* ws1 = (const float*)d_in[8];  const float* wn1 = (const float*)d_in[9];  const float* bb1 = (const float*)d_in[10];
    const float* ws2 = (const float*)d_in[11]; const float* wn2 = (const float*)d_in[12]; const float* bb2 = (const float*)d_in[13];
    const float* ws3 = (const float*)d_in[14]; const float* wn3 = (const float*)d_in[15]; const float* bb3 = (const float*)d_in[16];
    const float* wd1 = (const float*)d_in[17]; const float* bd1 = (const float*)d_in[18];
    const float* wd2 = (const float*)d_in[19]; const float* bd2 = (const float*)d_in[20];

    int N = in_sizes[0] / 3;
    int E = in_sizes[1] / 2;
    int G = out_size / 256;
    const int* esrc_in = eidx;
    const int* edst_in = eidx + E;

    char* base = (char*)d_ws;
    size_t off = 0;
    auto alloc = [&](size_t bytes) -> void* {
        void* p = base + off;
        off = (off + bytes + 255) & ~(size_t)255;
        return p;
    };
    int*   cnt      = (int*)alloc((size_t)(N + 1) * 4);
    int*   rowstart = (int*)alloc((size_t)(N + 1) * 4);
    int*   cursor   = (int*)alloc((size_t)N * 4);
    int*   esrc     = (int*)alloc((size_t)E * 4);
    float* degf     = (float*)alloc((size_t)N * 4);
    int*   chunksum = (int*)alloc((size_t)256 * 4);
    float* X0       = (float*)alloc((size_t)N * 128 * 4);  // [x | Sx/deg]
    float* X3       = (float*)alloc((size_t)N * 512 * 4);  // [h0,h1,h2 | Sx? no: Sh0,Sh1,Sh2]
    float* NF       = (float*)alloc((size_t)N * 256 * 4);
    float* pooled   = (float*)alloc((size_t)G * 512 * 4);
    float* hid      = (float*)alloc((size_t)G * 512 * 4);
    float* pmax     = (float*)alloc((size_t)G * 256 * 4);
    float* psum     = (float*)alloc((size_t)G * 256 * 4);
    int*   gcnt     = (int*)alloc((size_t)G * 4);
    unsigned short* xb  = (unsigned short*)alloc((size_t)N * 64 * 2);
    unsigned short* h0b = (unsigned short*)alloc((size_t)N * 64 * 2);
    unsigned short* h1b = (unsigned short*)alloc((size_t)N * 64 * 2);
    unsigned short* h2b = (unsigned short*)alloc((size_t)N * 128 * 2);

    // ---- CSR build ----
    hipMemsetAsync(cnt, 0, (size_t)(N + 1) * 4, stream);
    hist_k<<<(E + 255) / 256, 256, 0, stream>>>(edst_in, cnt, E);
    int PB = (N + SCHUNK - 1) / SCHUNK;
    scan_part<<<PB, 256, 0, stream>>>(cnt, rowstart, chunksum, N);
    scan_tops<<<1, 64, 0, stream>>>(chunksum, rowstart, PB, N);
    scan_fix<<<PB, 256, 0, stream>>>(cnt, rowstart, chunksum, cursor, degf, N);
    scatter_k<<<(E + 255) / 256, 256, 0, stream>>>(esrc_in, edst_in, cursor, esrc, E);

    // ---- projection ----
    proj_k<<<(N * 64 + 255) / 256, 256, 0, stream>>>(pos, w_proj, b_proj, X0, xb, N);

    int ab = (N + 3) / 4;
    int mb = (N + 63) / 64;

    // layer 0: agg(x) via xb -> X0 cols 64..128; gemm -> h0 (X3 cols 0..64) + h0b
    agg_bf<64><<<ab, 256, 0, stream>>>(xb, X0, 128, 64, rowstart, esrc, degf, N);
    gemm_lrelu<128, 64><<<dim3(mb, 1), 256, 0, stream>>>(
        X0, 128, 0, 128, X0, 128, 0, ws0, wn0, bb0, X3, 512, 0, h0b, N, 1);

    // layer 1: agg(h0) -> X3 cols 256..320; gemm -> h1 (X3 cols 64..128) + h1b
    agg_bf<64><<<ab, 256, 0, stream>>>(h0b, X3, 512, 256, rowstart, esrc, degf, N);
    gemm_lrelu<128, 64><<<dim3(mb, 1), 256, 0, stream>>>(
        X3, 512, 0, 64, X3, 512, 256, ws1, wn1, bb1, X3, 512, 64, h1b, N, 1);

    // layer 2: agg(h1) -> X3 cols 320..384; gemm -> h2 (X3 cols 128..256) + h2b
    agg_bf<64><<<ab, 256, 0, stream>>>(h1b, X3, 512, 320, rowstart, esrc, degf, N);
    gemm_lrelu<128, 128><<<dim3(mb, 2), 256, 0, stream>>>(
        X3, 512, 64, 64, X3, 512, 320, ws2, wn2, bb2, X3, 512, 128, h2b, N, 1);

    // layer 3: agg(h2) -> X3 cols 384..512; K=512 MFMA GEMM -> NF
    agg_bf<128><<<ab, 256, 0, stream>>>(h2b, X3, 512, 384, rowstart, esrc, degf, N);
    gemm_mfma<512, 256><<<dim3(mb, 4), 256, 0, stream>>>(
        X3, 512, ws3, wn3, bb3, NF, 256, N, 1);

    // ---- pooling (two-stage, parallel) ----
    pool_init<<<(G * 256 + 255) / 256, 256, 0, stream>>>(pmax, psum, gcnt, G);
    pool_partial<<<(N + PCHUNK - 1) / PCHUNK, 256, 0, stream>>>(NF, batch, pmax, psum, gcnt, N);
    pool_final<<<(G * 256 + 255) / 256, 256, 0, stream>>>(pmax, psum, gcnt, pooled, G);

    // ---- dense head ----
    gemm_lrelu<512, 512><<<dim3((G + 63) / 64, 8), 256, 0, stream>>>(
        pooled, 512, 0, 512, pooled, 512, 0, wd1, wd1 + 256 * 512, bd1, hid, 512, 0, nullptr, G, 1);
    gemm_lrelu<512, 256><<<dim3((G + 63) / 64, 4), 256, 0, stream>>>(
        hid, 512, 0, 512, hid, 512, 0, wd2, wd2 + 256 * 256, bd2, (float*)d_out, 256, 0, nullptr, G, 0);
}

// Round 5
// 428.985 us; speedup vs baseline: 2.3722x; 1.5648x over previous
//
#include <hip/hip_runtime.h>
#include <math.h>

typedef _Float16 f16x8 __attribute__((ext_vector_type(8)));
typedef unsigned short us8 __attribute__((ext_vector_type(8)));
typedef float f32x4 __attribute__((ext_vector_type(4)));

__device__ inline unsigned short f2h(float f) {
    _Float16 h = (_Float16)f;
    return *(unsigned short*)&h;
}
__device__ inline float h2f(unsigned short u) {
    _Float16 h = *(_Float16*)&u;
    return (float)h;
}

// ---------------------------------------------------------------- histogram
__global__ __launch_bounds__(256)
void hist_k(const int* __restrict__ edst, int* __restrict__ cnt, int E) {
    int t = blockIdx.x * 256 + threadIdx.x;
    if (t < E) atomicAdd(&cnt[edst[t]], 1);
}

// ---------------------------------------------------------------- parallel scan (3 stages)
#define SCHUNK 1024
__global__ __launch_bounds__(256)
void scan_part(const int* __restrict__ cnt, int* __restrict__ rowstart,
               int* __restrict__ psum, int n) {
    __shared__ int wsum[4];
    int b = blockIdx.x;
    int base = b * SCHUNK;
    int tid = threadIdx.x, lane = tid & 63, wid = tid >> 6;
    int idx = base + tid * 4;
    int v[4]; int s = 0;
    #pragma unroll
    for (int j = 0; j < 4; j++) { v[j] = (idx + j < n) ? cnt[idx + j] : 0; s += v[j]; }
    int x = s;
    for (int d = 1; d < 64; d <<= 1) { int y = __shfl_up(x, d); if (lane >= d) x += y; }
    if (lane == 63) wsum[wid] = x;
    __syncthreads();
    int off = 0;
    for (int w = 0; w < wid; w++) off += wsum[w];
    int excl = x - s + off;
    int run = excl;
    #pragma unroll
    for (int j = 0; j < 4; j++) {
        if (idx + j < n) rowstart[idx + j] = run;
        run += v[j];
    }
    if (tid == 255) psum[b] = off + x;
}

__global__ __launch_bounds__(64)
void scan_tops(int* __restrict__ psum, int* __restrict__ rowstart, int PB, int n) {
    int lane = threadIdx.x;
    int v = (lane < PB) ? psum[lane] : 0;
    int x = v;
    for (int d = 1; d < 64; d <<= 1) { int y = __shfl_up(x, d); if (lane >= d) x += y; }
    if (lane < PB) psum[lane] = x - v;
    if (lane == 63) rowstart[n] = x;
}

__global__ __launch_bounds__(256)
void scan_fix(const int* __restrict__ cnt, int* __restrict__ rowstart,
              const int* __restrict__ psum, int* __restrict__ cursor,
              float* __restrict__ degf, int n) {
    int b = blockIdx.x;
    int base = b * SCHUNK;
    int tid = threadIdx.x;
    int add = psum[b];
    #pragma unroll
    for (int k = 0; k < 4; k++) {
        int i = base + k * 256 + tid;
        if (i < n) {
            int r = rowstart[i] + add;
            rowstart[i] = r; cursor[i] = r;
            int c = cnt[i];
            degf[i] = (float)(c > 0 ? c : 1);
        }
    }
}

// ---------------------------------------------------------------- scatter into CSR
__global__ __launch_bounds__(256)
void scatter_k(const int* __restrict__ esrc_in, const int* __restrict__ edst_in,
               int* __restrict__ cursor, int* __restrict__ esrc, int E) {
    int t = blockIdx.x * 256 + threadIdx.x;
    if (t < E) {
        int p = atomicAdd(&cursor[edst_in[t]], 1);
        esrc[p] = esrc_in[t];
    }
}

// ---------------------------------------------------------------- weight transpose-convert: WT[n][k] f16
// Ws (K2 x FOUT), Wn (K2 x FOUT) stacked along k; out [FOUT][2*K2]
__global__ __launch_bounds__(256)
void wcvt(const float* __restrict__ Ws, const float* __restrict__ Wn,
          int K2, int FOUT, unsigned short* __restrict__ out) {
    int t = blockIdx.x * 256 + threadIdx.x;
    int total = 2 * K2 * FOUT;
    if (t >= total) return;
    int k = t / FOUT, n = t - k * FOUT;
    float v = (k < K2) ? Ws[k * FOUT + n] : Wn[(k - K2) * FOUT + n];
    out[(size_t)n * (2 * K2) + k] = f2h(v);
}

// ---------------------------------------------------------------- node projection pos[N,3] @ w[3,64] + b -> f16
__global__ __launch_bounds__(256)
void proj_k(const float* __restrict__ pos, const float* __restrict__ w,
            const float* __restrict__ b, unsigned short* __restrict__ XB0, int n_nodes) {
    int t = blockIdx.x * 256 + threadIdx.x;
    int n = t >> 6, f = t & 63;
    if (n >= n_nodes) return;
    float p0 = pos[n * 3 + 0], p1 = pos[n * 3 + 1], p2 = pos[n * 3 + 2];
    float v = b[f] + p0 * w[f] + p1 * w[64 + f] + p2 * w[128 + f];
    XB0[(size_t)n * 128 + f] = f2h(v);
}

// ---------------------------------------------------------------- CSR mean-aggregate, f16, pipelined gathers
// F=64: half-wave per row (lanes 0-31 even edges, 32-63 odd), 4B/lane, 8 rows in flight.
// F=128: full wave per row, 4B/lane, 4 rows in flight.
// src/dst pre-offset to column start; strides in halves.
template <int F>
__global__ __launch_bounds__(256)
void agg_f16(const unsigned short* __restrict__ src, int sstr,
             unsigned short* __restrict__ dst, int dstr,
             const int* __restrict__ rowstart, const int* __restrict__ esrc,
             const float* __restrict__ degf, int n_nodes) {
    int wave = threadIdx.x >> 6;
    int lane = threadIdx.x & 63;
    int n = blockIdx.x * 4 + wave;
    if (n >= n_nodes) return;
    const int ST = (F == 64) ? 2 : 1;
    int half = (F == 64) ? (lane >> 5) : 0;
    int li   = (F == 64) ? (lane & 31) : lane;
    int e0 = rowstart[n], e1 = rowstart[n + 1];
    float a0 = 0.f, a1 = 0.f;
    int e = e0 + half;
    for (; e + 3 * ST < e1; e += 4 * ST) {
        int s0 = esrc[e], s1 = esrc[e + ST], s2 = esrc[e + 2 * ST], s3 = esrc[e + 3 * ST];
        unsigned p0 = *(const unsigned*)&src[(size_t)s0 * sstr + 2 * li];
        unsigned p1 = *(const unsigned*)&src[(size_t)s1 * sstr + 2 * li];
        unsigned p2 = *(const unsigned*)&src[(size_t)s2 * sstr + 2 * li];
        unsigned p3 = *(const unsigned*)&src[(size_t)s3 * sstr + 2 * li];
        a0 += h2f((unsigned short)(p0 & 0xffffu)) + h2f((unsigned short)(p1 & 0xffffu))
            + h2f((unsigned short)(p2 & 0xffffu)) + h2f((unsigned short)(p3 & 0xffffu));
        a1 += h2f((unsigned short)(p0 >> 16)) + h2f((unsigned short)(p1 >> 16))
            + h2f((unsigned short)(p2 >> 16)) + h2f((unsigned short)(p3 >> 16));
    }
    for (; e < e1; e += ST) {
        int s = esrc[e];
        unsigned p = *(const unsigned*)&src[(size_t)s * sstr + 2 * li];
        a0 += h2f((unsigned short)(p & 0xffffu));
        a1 += h2f((unsigned short)(p >> 16));
    }
    if (F == 64) { a0 += __shfl_xor(a0, 32); a1 += __shfl_xor(a1, 32); }
    float inv = 1.0f / degf[n];
    unsigned out = (unsigned)f2h(a0 * inv) | ((unsigned)f2h(a1 * inv) << 16);
    if (F != 64 || lane < 32)
        *(unsigned*)&dst[(size_t)n * dstr + 2 * li] = out;
}

// ---------------------------------------------------------------- f16 MFMA GEMM: out = lrelu(A @ W + bias)
// A f16 [M x astr], k<KA1 at col ac1+k, else col ac2+(k-KA1). Wh f16 transposed [FOUT][K].
// BN = FOUT (single pass over A). Block: 4 waves, BM=64.
template <int K, int FOUT>
__global__ __launch_bounds__(256)
void gemm_f16(const unsigned short* __restrict__ A, int astr, int KA1, int ac1, int ac2,
              const unsigned short* __restrict__ Wh, const float* __restrict__ bias,
              float* __restrict__ Df, int dfs,
              unsigned short* __restrict__ Db, int dbs, int dbc,
              int M, int doRelu) {
    const int LDH = 40;  // halves per LDS row (80 B): 2-way max on frag reads
    __shared__ unsigned short As[64 * LDH];
    __shared__ unsigned short Bs[FOUT * LDH];
    int t = threadIdx.x;
    int w = t >> 6, lane = t & 63;
    int lm = lane & 15, kb = lane >> 4;
    int m0 = blockIdx.x * 64;
    int arow = t >> 2;
    int akq  = (t & 3) * 8;

    f32x4 acc[FOUT / 16] = {};

    for (int k0 = 0; k0 < K; k0 += 32) {
        // ---- stage A ----
        {
            int kk = k0 + akq;
            int col = (kk < KA1) ? (ac1 + kk) : (ac2 + (kk - KA1));
            int gm = m0 + arow;
            us8 av = us8{0, 0, 0, 0, 0, 0, 0, 0};
            if (gm < M) av = *(const us8*)&A[(size_t)gm * astr + col];
            *(us8*)&As[arow * LDH + akq] = av;
        }
        // ---- stage B from transposed f16 weights ----
        #pragma unroll
        for (int i = 0; i < FOUT / 64; i++) {
            int idx = t + i * 256;
            int bc = idx >> 2, kc = (idx & 3) * 8;
            *(us8*)&Bs[bc * LDH + kc] = *(const us8*)&Wh[(size_t)bc * K + k0 + kc];
        }
        __syncthreads();
        f16x8 af = *(const f16x8*)&As[(w * 16 + lm) * LDH + kb * 8];
        #pragma unroll
        for (int nt = 0; nt < FOUT / 16; nt++) {
            f16x8 bf = *(const f16x8*)&Bs[(nt * 16 + lm) * LDH + kb * 8];
            acc[nt] = __builtin_amdgcn_mfma_f32_16x16x32_f16(af, bf, acc[nt], 0, 0, 0);
        }
        __syncthreads();
    }

    #pragma unroll
    for (int nt = 0; nt < FOUT / 16; nt++) {
        int gn = nt * 16 + lm;
        float bv = bias[gn];
        #pragma unroll
        for (int r = 0; r < 4; r++) {
            int gm = m0 + w * 16 + kb * 4 + r;
            if (gm >= M) continue;
            float v = acc[nt][r] + bv;
            if (doRelu) v = (v > 0.f) ? v : 0.01f * v;
            if (Df) Df[(size_t)gm * dfs + gn] = v;
            if (Db) Db[(size_t)gm * dbs + dbc + gn] = f2h(v);
        }
    }
}

// ---------------------------------------------------------------- fp32 fused GEMM (dense head)
template <int K, int FOUT>
__global__ __launch_bounds__(256)
void gemm_lrelu(const float* __restrict__ A1, int a1s, int a1c, int KA1,
                const float* __restrict__ A2, int a2s, int a2c,
                const float* __restrict__ W1, const float* __restrict__ W2,
                const float* __restrict__ bias,
                float* __restrict__ D, int dstr, int dcol, int M, int doRelu) {
    const int BM = 64, BN = 64, BK = 16;
    __shared__ float As[BK][BM];
    __shared__ float Bs[BK][BN];
    int tid = threadIdx.x;
    int m0 = blockIdx.x * BM;
    int n0 = blockIdx.y * BN;
    int tx = tid & 15;
    int ty = tid >> 4;
    float acc[4][4] = {};
    int mA = tid >> 2;
    int kA = (tid & 3) * 4;
    int kB = tid >> 4;
    int nB = (tid & 15) * 4;
    for (int k0 = 0; k0 < K; k0 += BK) {
        int kk = k0 + kA;
        const float* Ap; int Asr; int Acc;
        if (kk < KA1) { Ap = A1; Asr = a1s; Acc = a1c + kk; }
        else          { Ap = A2; Asr = a2s; Acc = a2c + (kk - KA1); }
        int gm = m0 + mA;
        float4 av;
        if (gm < M) av = *(const float4*)&Ap[(size_t)gm * Asr + Acc];
        else        av = float4{0.f, 0.f, 0.f, 0.f};
        As[kA + 0][mA] = av.x; As[kA + 1][mA] = av.y;
        As[kA + 2][mA] = av.z; As[kA + 3][mA] = av.w;
        int kw = k0 + kB;
        const float* Wp; int kwl;
        if (kw < K / 2) { Wp = W1; kwl = kw; } else { Wp = W2; kwl = kw - K / 2; }
        float4 bv = *(const float4*)&Wp[(size_t)kwl * FOUT + n0 + nB];
        *(float4*)&Bs[kB][nB] = bv;
        __syncthreads();
        #pragma unroll
        for (int k = 0; k < BK; k++) {
            float a[4], b[4];
            *(float4*)a = *(const float4*)&As[k][ty * 4];
            *(float4*)b = *(const float4*)&Bs[k][tx * 4];
            #pragma unroll
            for (int i = 0; i < 4; i++)
                #pragma unroll
                for (int j = 0; j < 4; j++)
                    acc[i][j] += a[i] * b[j];
        }
        __syncthreads();
    }
    #pragma unroll
    for (int i = 0; i < 4; i++) {
        int gm = m0 + ty * 4 + i;
        if (gm >= M) continue;
        #pragma unroll
        for (int j = 0; j < 4; j++) {
            int gn = n0 + tx * 4 + j;
            float v = acc[i][j] + bias[gn];
            if (doRelu) v = (v > 0.f) ? v : 0.01f * v;
            D[(size_t)gm * dstr + dcol + gn] = v;
        }
    }
}

// ---------------------------------------------------------------- pooling
__global__ __launch_bounds__(256)
void pool_init(float* __restrict__ pmax, float* __restrict__ psum,
               int* __restrict__ gcnt, int G) {
    int t = blockIdx.x * 256 + threadIdx.x;
    if (t < G * 256) { pmax[t] = -INFINITY; psum[t] = 0.f; }
    if (t < G) gcnt[t] = 0;
}

__device__ inline void atomicMaxFloat(float* addr, float v) {
    if (v >= 0.f) atomicMax((int*)addr, __float_as_int(v));
    else          atomicMin((unsigned int*)addr, __float_as_uint(v));
}

#define PCHUNK 128
__global__ __launch_bounds__(256)
void pool_partial(const float* __restrict__ nf, const int* __restrict__ batch,
                  float* __restrict__ pmax, float* __restrict__ psum,
                  int* __restrict__ gcnt, int n_nodes) {
    __shared__ int bsh[PCHUNK];
    int c0 = blockIdx.x * PCHUNK;
    int c1 = min(c0 + PCHUNK, n_nodes);
    int f = threadIdx.x;
    for (int i = c0 + f; i < c1; i += 256) bsh[i - c0] = batch[i];
    __syncthreads();
    float mx = -INFINITY, sm = 0.f;
    int cur = bsh[0], segstart = c0;
    for (int i = c0; i < c1; i++) {
        int g = bsh[i - c0];
        if (g != cur) {
            atomicMaxFloat(&pmax[cur * 256 + f], mx);
            atomicAdd(&psum[cur * 256 + f], sm);
            if (f == 0) atomicAdd(&gcnt[cur], i - segstart);
            mx = -INFINITY; sm = 0.f; cur = g; segstart = i;
        }
        float v = nf[(size_t)i * 256 + f];
        mx = fmaxf(mx, v);
        sm += v;
    }
    atomicMaxFloat(&pmax[cur * 256 + f], mx);
    atomicAdd(&psum[cur * 256 + f], sm);
    if (f == 0) atomicAdd(&gcnt[cur], c1 - segstart);
}

__global__ __launch_bounds__(256)
void pool_final(const float* __restrict__ pmax, const float* __restrict__ psum,
                const int* __restrict__ gcnt, float* __restrict__ pooled, int G) {
    int t = blockIdx.x * 256 + threadIdx.x;
    if (t >= G * 256) return;
    int g = t >> 8, f = t & 255;
    int c = gcnt[g];
    float mx = pmax[t];
    if (c == 0) mx = 0.f;
    pooled[g * 512 + f] = mx;
    pooled[g * 512 + 256 + f] = psum[t] / (float)(c > 0 ? c : 1);
}

// ---------------------------------------------------------------- launcher
extern "C" void kernel_launch(void* const* d_in, const int* in_sizes, int n_in,
                              void* d_out, int out_size, void* d_ws, size_t ws_size,
                              hipStream_t stream) {
    const float* pos   = (const float*)d_in[0];
    const int*   eidx  = (const int*)d_in[1];
    const int*   batch = (const int*)d_in[2];
    const float* w_proj = (const float*)d_in[3];
    const float* b_proj = (const float*)d_in[4];
    const float* ws0 = (const float*)d_in[5];  const float* wn0 = (const float*)d_in[6];  const float* bb0 = (const float*)d_in[7];
    const float* ws1 = (const float*)d_in[8];  const float* wn1 = (const float*)d_in[9];  const float* bb1 = (const float*)d_in[10];
    const float* ws2 = (const float*)d_in[11]; const float* wn2 = (const float*)d_in[12]; const float* bb2 = (const float*)d_in[13];
    const float* ws3 = (const float*)d_in[14]; const float* wn3 = (const float*)d_in[15]; const float* bb3 = (const float*)d_in[16];
    const float* wd1 = (const float*)d_in[17]; const float* bd1 = (const float*)d_in[18];
    const float* wd2 = (const float*)d_in[19]; const float* bd2 = (const float*)d_in[20];

    int N = in_sizes[0] / 3;
    int E = in_sizes[1] / 2;
    int G = out_size / 256;
    const int* esrc_in = eidx;
    const int* edst_in = eidx + E;

    char* base = (char*)d_ws;
    size_t off = 0;
    auto alloc = [&](size_t bytes) -> void* {
        void* p = base + off;
        off = (off + bytes + 255) & ~(size_t)255;
        return p;
    };
    int*   cnt      = (int*)alloc((size_t)(N + 1) * 4);
    int*   rowstart = (int*)alloc((size_t)(N + 1) * 4);
    int*   cursor   = (int*)alloc((size_t)N * 4);
    int*   esrc     = (int*)alloc((size_t)E * 4);
    float* degf     = (float*)alloc((size_t)N * 4);
    int*   chunksum = (int*)alloc((size_t)256 * 4);
    unsigned short* XB0 = (unsigned short*)alloc((size_t)N * 128 * 2);  // [x | Sx]
    unsigned short* XB  = (unsigned short*)alloc((size_t)N * 512 * 2);  // [h0 h1 h2 | Sh0 Sh1 Sh2]
    float* NF       = (float*)alloc((size_t)N * 256 * 4);
    float* pooled   = (float*)alloc((size_t)G * 512 * 4);
    float* hid      = (float*)alloc((size_t)G * 512 * 4);
    float* pmax     = (float*)alloc((size_t)G * 256 * 4);
    float* psum     = (float*)alloc((size_t)G * 256 * 4);
    int*   gcnt     = (int*)alloc((size_t)G * 4);
    unsigned short* WT0 = (unsigned short*)alloc((size_t)64 * 128 * 2);
    unsigned short* WT1 = (unsigned short*)alloc((size_t)64 * 128 * 2);
    unsigned short* WT2 = (unsigned short*)alloc((size_t)128 * 128 * 2);
    unsigned short* WT3 = (unsigned short*)alloc((size_t)256 * 512 * 2);

    // ---- weight prep (f16, transposed) ----
    wcvt<<<(2 * 64 * 64 + 255) / 256, 256, 0, stream>>>(ws0, wn0, 64, 64, WT0);
    wcvt<<<(2 * 64 * 64 + 255) / 256, 256, 0, stream>>>(ws1, wn1, 64, 64, WT1);
    wcvt<<<(2 * 64 * 128 + 255) / 256, 256, 0, stream>>>(ws2, wn2, 64, 128, WT2);
    wcvt<<<(2 * 256 * 256 + 255) / 256, 256, 0, stream>>>(ws3, wn3, 256, 256, WT3);

    // ---- CSR build ----
    (void)hipMemsetAsync(cnt, 0, (size_t)(N + 1) * 4, stream);
    hist_k<<<(E + 255) / 256, 256, 0, stream>>>(edst_in, cnt, E);
    int PB = (N + SCHUNK - 1) / SCHUNK;
    scan_part<<<PB, 256, 0, stream>>>(cnt, rowstart, chunksum, N);
    scan_tops<<<1, 64, 0, stream>>>(chunksum, rowstart, PB, N);
    scan_fix<<<PB, 256, 0, stream>>>(cnt, rowstart, chunksum, cursor, degf, N);
    scatter_k<<<(E + 255) / 256, 256, 0, stream>>>(esrc_in, edst_in, cursor, esrc, E);

    // ---- projection ----
    proj_k<<<(N * 64 + 255) / 256, 256, 0, stream>>>(pos, w_proj, b_proj, XB0, N);

    int ab = (N + 3) / 4;
    int mb = (N + 63) / 64;

    // layer 0: agg(x) -> XB0 cols 64..128; gemm -> h0 (XB cols 0..64)
    agg_f16<64><<<ab, 256, 0, stream>>>(XB0, 128, XB0 + 64, 128, rowstart, esrc, degf, N);
    gemm_f16<128, 64><<<mb, 256, 0, stream>>>(
        XB0, 128, 128, 0, 0, WT0, bb0, nullptr, 0, XB, 512, 0, N, 1);

    // layer 1: agg(h0) -> XB cols 256..320; gemm -> h1 (XB cols 64..128)
    agg_f16<64><<<ab, 256, 0, stream>>>(XB, 512, XB + 256, 512, rowstart, esrc, degf, N);
    gemm_f16<128, 64><<<mb, 256, 0, stream>>>(
        XB, 512, 64, 0, 256, WT1, bb1, nullptr, 0, XB, 512, 64, N, 1);

    // layer 2: agg(h1) -> XB cols 320..384; gemm -> h2 (XB cols 128..256)
    agg_f16<64><<<ab, 256, 0, stream>>>(XB + 64, 512, XB + 320, 512, rowstart, esrc, degf, N);
    gemm_f16<128, 128><<<mb, 256, 0, stream>>>(
        XB, 512, 64, 64, 320, WT2, bb2, nullptr, 0, XB, 512, 128, N, 1);

    // layer 3: agg(h2) -> XB cols 384..512; K=512 gemm -> NF fp32
    agg_f16<128><<<ab, 256, 0, stream>>>(XB + 128, 512, XB + 384, 512, rowstart, esrc, degf, N);
    gemm_f16<512, 256><<<mb, 256, 0, stream>>>(
        XB, 512, 512, 0, 0, WT3, bb3, NF, 256, nullptr, 0, 0, N, 1);

    // ---- pooling (two-stage, parallel) ----
    pool_init<<<(G * 256 + 255) / 256, 256, 0, stream>>>(pmax, psum, gcnt, G);
    pool_partial<<<(N + PCHUNK - 1) / PCHUNK, 256, 0, stream>>>(NF, batch, pmax, psum, gcnt, N);
    pool_final<<<(G * 256 + 255) / 256, 256, 0, stream>>>(pmax, psum, gcnt, pooled, G);

    // ---- dense head (fp32) ----
    gemm_lrelu<512, 512><<<dim3((G + 63) / 64, 8), 256, 0, stream>>>(
        pooled, 512, 0, 512, pooled, 512, 0, wd1, wd1 + 256 * 512, bd1, hid, 512, 0, G, 1);
    gemm_lrelu<512, 256><<<dim3((G + 63) / 64, 4), 256, 0, stream>>>(
        hid, 512, 0, 512, hid, 512, 0, wd2, wd2 + 256 * 256, bd2, (float*)d_out, 256, 0, G, 0);
}

// Round 6
// 407.693 us; speedup vs baseline: 2.4961x; 1.0522x over previous
//
#include <hip/hip_runtime.h>
#include <math.h>

typedef _Float16 f16x8 __attribute__((ext_vector_type(8)));
typedef unsigned short us8 __attribute__((ext_vector_type(8)));
typedef float f32x4 __attribute__((ext_vector_type(4)));

__device__ inline unsigned short f2h(float f) {
    _Float16 h = (_Float16)f;
    return *(unsigned short*)&h;
}
__device__ inline float h2f(unsigned short u) {
    _Float16 h = *(_Float16*)&u;
    return (float)h;
}

// ---------------------------------------------------------------- histogram
__global__ __launch_bounds__(256)
void hist_k(const int* __restrict__ edst, int* __restrict__ cnt, int E) {
    int t = blockIdx.x * 256 + threadIdx.x;
    if (t < E) atomicAdd(&cnt[edst[t]], 1);
}

// ---------------------------------------------------------------- parallel scan (3 stages)
#define SCHUNK 1024
__global__ __launch_bounds__(256)
void scan_part(const int* __restrict__ cnt, int* __restrict__ rowstart,
               int* __restrict__ psum, int n) {
    __shared__ int wsum[4];
    int b = blockIdx.x;
    int base = b * SCHUNK;
    int tid = threadIdx.x, lane = tid & 63, wid = tid >> 6;
    int idx = base + tid * 4;
    int v[4]; int s = 0;
    #pragma unroll
    for (int j = 0; j < 4; j++) { v[j] = (idx + j < n) ? cnt[idx + j] : 0; s += v[j]; }
    int x = s;
    for (int d = 1; d < 64; d <<= 1) { int y = __shfl_up(x, d); if (lane >= d) x += y; }
    if (lane == 63) wsum[wid] = x;
    __syncthreads();
    int off = 0;
    for (int w = 0; w < wid; w++) off += wsum[w];
    int excl = x - s + off;
    int run = excl;
    #pragma unroll
    for (int j = 0; j < 4; j++) {
        if (idx + j < n) rowstart[idx + j] = run;
        run += v[j];
    }
    if (tid == 255) psum[b] = off + x;
}

__global__ __launch_bounds__(64)
void scan_tops(int* __restrict__ psum, int* __restrict__ rowstart, int PB, int n) {
    int lane = threadIdx.x;
    int v = (lane < PB) ? psum[lane] : 0;
    int x = v;
    for (int d = 1; d < 64; d <<= 1) { int y = __shfl_up(x, d); if (lane >= d) x += y; }
    if (lane < PB) psum[lane] = x - v;
    if (lane == 63) rowstart[n] = x;
}

__global__ __launch_bounds__(256)
void scan_fix(const int* __restrict__ cnt, int* __restrict__ rowstart,
              const int* __restrict__ psum, int* __restrict__ cursor,
              float* __restrict__ degf, int n) {
    int b = blockIdx.x;
    int base = b * SCHUNK;
    int tid = threadIdx.x;
    int add = psum[b];
    #pragma unroll
    for (int k = 0; k < 4; k++) {
        int i = base + k * 256 + tid;
        if (i < n) {
            int r = rowstart[i] + add;
            rowstart[i] = r; cursor[i] = r;
            int c = cnt[i];
            degf[i] = (float)(c > 0 ? c : 1);
        }
    }
}

// ---------------------------------------------------------------- scatter into CSR
__global__ __launch_bounds__(256)
void scatter_k(const int* __restrict__ esrc_in, const int* __restrict__ edst_in,
               int* __restrict__ cursor, int* __restrict__ esrc, int E) {
    int t = blockIdx.x * 256 + threadIdx.x;
    if (t < E) {
        int p = atomicAdd(&cursor[edst_in[t]], 1);
        esrc[p] = esrc_in[t];
    }
}

// ---------------------------------------------------------------- weight transpose-convert: WT[n][k] f16
__global__ __launch_bounds__(256)
void wcvt(const float* __restrict__ Ws, const float* __restrict__ Wn,
          int K2, int FOUT, unsigned short* __restrict__ out) {
    int t = blockIdx.x * 256 + threadIdx.x;
    int total = 2 * K2 * FOUT;
    if (t >= total) return;
    int k = t / FOUT, n = t - k * FOUT;
    float v = (k < K2) ? Ws[k * FOUT + n] : Wn[(k - K2) * FOUT + n];
    out[(size_t)n * (2 * K2) + k] = f2h(v);
}

// ---------------------------------------------------------------- node projection -> f16
__global__ __launch_bounds__(256)
void proj_k(const float* __restrict__ pos, const float* __restrict__ w,
            const float* __restrict__ b, unsigned short* __restrict__ XB0, int n_nodes) {
    int t = blockIdx.x * 256 + threadIdx.x;
    int n = t >> 6, f = t & 63;
    if (n >= n_nodes) return;
    float p0 = pos[n * 3 + 0], p1 = pos[n * 3 + 1], p2 = pos[n * 3 + 2];
    float v = b[f] + p0 * w[f] + p1 * w[64 + f] + p2 * w[128 + f];
    XB0[(size_t)n * 128 + f] = f2h(v);
}

// ---------------------------------------------------------------- CSR mean-aggregate, f16, pipelined gathers
template <int F>
__global__ __launch_bounds__(256)
void agg_f16(const unsigned short* __restrict__ src, int sstr,
             unsigned short* __restrict__ dst, int dstr,
             const int* __restrict__ rowstart, const int* __restrict__ esrc,
             const float* __restrict__ degf, int n_nodes) {
    int wave = threadIdx.x >> 6;
    int lane = threadIdx.x & 63;
    int n = blockIdx.x * 4 + wave;
    if (n >= n_nodes) return;
    const int ST = (F == 64) ? 2 : 1;
    int half = (F == 64) ? (lane >> 5) : 0;
    int li   = (F == 64) ? (lane & 31) : lane;
    int e0 = rowstart[n], e1 = rowstart[n + 1];
    float a0 = 0.f, a1 = 0.f;
    int e = e0 + half;
    for (; e + 3 * ST < e1; e += 4 * ST) {
        int s0 = esrc[e], s1 = esrc[e + ST], s2 = esrc[e + 2 * ST], s3 = esrc[e + 3 * ST];
        unsigned p0 = *(const unsigned*)&src[(size_t)s0 * sstr + 2 * li];
        unsigned p1 = *(const unsigned*)&src[(size_t)s1 * sstr + 2 * li];
        unsigned p2 = *(const unsigned*)&src[(size_t)s2 * sstr + 2 * li];
        unsigned p3 = *(const unsigned*)&src[(size_t)s3 * sstr + 2 * li];
        a0 += h2f((unsigned short)(p0 & 0xffffu)) + h2f((unsigned short)(p1 & 0xffffu))
            + h2f((unsigned short)(p2 & 0xffffu)) + h2f((unsigned short)(p3 & 0xffffu));
        a1 += h2f((unsigned short)(p0 >> 16)) + h2f((unsigned short)(p1 >> 16))
            + h2f((unsigned short)(p2 >> 16)) + h2f((unsigned short)(p3 >> 16));
    }
    for (; e < e1; e += ST) {
        int s = esrc[e];
        unsigned p = *(const unsigned*)&src[(size_t)s * sstr + 2 * li];
        a0 += h2f((unsigned short)(p & 0xffffu));
        a1 += h2f((unsigned short)(p >> 16));
    }
    if (F == 64) { a0 += __shfl_xor(a0, 32); a1 += __shfl_xor(a1, 32); }
    float inv = 1.0f / degf[n];
    unsigned out = (unsigned)f2h(a0 * inv) | ((unsigned)f2h(a1 * inv) << 16);
    if (F != 64 || lane < 32)
        *(unsigned*)&dst[(size_t)n * dstr + 2 * li] = out;
}

__device__ inline void atomicMaxFloat(float* addr, float v) {
    if (v >= 0.f) atomicMax((int*)addr, __float_as_int(v));
    else          atomicMin((unsigned int*)addr, __float_as_uint(v));
}

// ---------------------------------------------------------------- register-blocked f16 MFMA GEMM
// Block: 256 thr (4 waves, 2x2), BM=128, BN columns (64 or 128). Wave tile 64 x BN/2.
// LDS fragment-major layout: 16B unit u = rblk*64 + ak*16 + rlow; frag reads are linear.
// POOL=1: fused segmented max/sum pooling epilogue (no activation matrix written).
template <int K, int BN, int POOL>
__global__ __launch_bounds__(256)
void gemm_rb(const unsigned short* __restrict__ A, int astr, int KA1, int ac1, int ac2,
             const unsigned short* __restrict__ Wh, const float* __restrict__ bias,
             unsigned short* __restrict__ Db, int dbs, int dbc,
             float* __restrict__ pmax, float* __restrict__ psum,
             const int* __restrict__ batch, int M) {
    const int NT = K / 32;
    const int NTB = BN / 32;   // n-frags per wave
    __shared__ unsigned short As[128 * 32];
    __shared__ unsigned short Bs[BN * 32];
    __shared__ int bsh[128];
    int t = threadIdx.x;
    int w = t >> 6, lane = t & 63;
    int wm = w >> 1, wn = w & 1;
    int lm = lane & 15, kb = lane >> 4;
    int m0 = blockIdx.x * 128;
    int n0 = blockIdx.y * BN;
    if (POOL) { if (t < 128) bsh[t] = (m0 + t < M) ? batch[m0 + t] : 0; }

    f32x4 acc[4][NTB] = {};
    us8 ra[2];
    us8 rb_[BN / 64];
    us8 zero8 = us8{0, 0, 0, 0, 0, 0, 0, 0};

    // prologue load (k0 = 0)
    #pragma unroll
    for (int i = 0; i < 2; i++) {
        int c = t + 256 * i; int r = ((c >> 6) << 4) + (c & 15); int kk = ((c >> 4) & 3) * 8;
        int col = (kk < KA1) ? ac1 + kk : ac2 + (kk - KA1);
        int gm = m0 + r;
        ra[i] = (gm < M) ? *(const us8*)&A[(size_t)gm * astr + col] : zero8;
    }
    #pragma unroll
    for (int i = 0; i < BN / 64; i++) {
        int c = t + 256 * i; int r = ((c >> 6) << 4) + (c & 15); int kk = ((c >> 4) & 3) * 8;
        rb_[i] = *(const us8*)&Wh[(size_t)(n0 + r) * K + kk];
    }

    for (int s = 0; s < NT; s++) {
        if (s) __syncthreads();
        #pragma unroll
        for (int i = 0; i < 2; i++) *(us8*)&As[(size_t)(t + 256 * i) * 8] = ra[i];
        #pragma unroll
        for (int i = 0; i < BN / 64; i++) *(us8*)&Bs[(size_t)(t + 256 * i) * 8] = rb_[i];
        __syncthreads();
        if (s + 1 < NT) {
            int k0 = (s + 1) * 32;
            #pragma unroll
            for (int i = 0; i < 2; i++) {
                int c = t + 256 * i; int r = ((c >> 6) << 4) + (c & 15); int kk = k0 + ((c >> 4) & 3) * 8;
                int col = (kk < KA1) ? ac1 + kk : ac2 + (kk - KA1);
                int gm = m0 + r;
                ra[i] = (gm < M) ? *(const us8*)&A[(size_t)gm * astr + col] : zero8;
            }
            #pragma unroll
            for (int i = 0; i < BN / 64; i++) {
                int c = t + 256 * i; int r = ((c >> 6) << 4) + (c & 15); int kk = k0 + ((c >> 4) & 3) * 8;
                rb_[i] = *(const us8*)&Wh[(size_t)(n0 + r) * K + kk];
            }
        }
        f16x8 af[4];
        #pragma unroll
        for (int mf = 0; mf < 4; mf++)
            af[mf] = *(const f16x8*)&As[(size_t)((wm * 4 + mf) * 64 + lane) * 8];
        #pragma unroll
        for (int nt = 0; nt < NTB; nt++) {
            f16x8 bf = *(const f16x8*)&Bs[(size_t)((wn * NTB + nt) * 64 + lane) * 8];
            #pragma unroll
            for (int mf = 0; mf < 4; mf++)
                acc[mf][nt] = __builtin_amdgcn_mfma_f32_16x16x32_f16(af[mf], bf, acc[mf][nt], 0, 0, 0);
        }
    }

    // epilogue
    #pragma unroll
    for (int nt = 0; nt < NTB; nt++) {
        int col = n0 + wn * (BN / 2) + nt * 16 + lm;
        float bv = bias[col];
        if (!POOL) {
            #pragma unroll
            for (int mf = 0; mf < 4; mf++) {
                #pragma unroll
                for (int r = 0; r < 4; r++) {
                    int rowl = wm * 64 + mf * 16 + kb * 4 + r;
                    int gm = m0 + rowl;
                    if (gm >= M) continue;
                    float v = acc[mf][nt][r] + bv;
                    v = (v > 0.f) ? v : 0.01f * v;
                    Db[(size_t)gm * dbs + dbc + col] = f2h(v);
                }
            }
        } else {
            int curg = -1; float mx = -INFINITY, sm = 0.f;
            #pragma unroll
            for (int mf = 0; mf < 4; mf++) {
                #pragma unroll
                for (int r = 0; r < 4; r++) {
                    int rowl = wm * 64 + mf * 16 + kb * 4 + r;
                    int gm = m0 + rowl;
                    if (gm >= M) continue;
                    int g = bsh[rowl];
                    if (g != curg) {
                        if (curg >= 0) {
                            atomicMaxFloat(&pmax[curg * 256 + col], mx);
                            atomicAdd(&psum[curg * 256 + col], sm);
                        }
                        curg = g; mx = -INFINITY; sm = 0.f;
                    }
                    float v = acc[mf][nt][r] + bv;
                    v = (v > 0.f) ? v : 0.01f * v;
                    mx = fmaxf(mx, v); sm += v;
                }
            }
            if (curg >= 0) {
                atomicMaxFloat(&pmax[curg * 256 + col], mx);
                atomicAdd(&psum[curg * 256 + col], sm);
            }
        }
    }
}

// ---------------------------------------------------------------- fp32 fused GEMM (dense head)
template <int K, int FOUT>
__global__ __launch_bounds__(256)
void gemm_lrelu(const float* __restrict__ A1, int a1s, int a1c, int KA1,
                const float* __restrict__ A2, int a2s, int a2c,
                const float* __restrict__ W1, const float* __restrict__ W2,
                const float* __restrict__ bias,
                float* __restrict__ D, int dstr, int dcol, int M, int doRelu) {
    const int BM = 64, BN = 64, BK = 16;
    __shared__ float As[BK][BM];
    __shared__ float Bs[BK][BN];
    int tid = threadIdx.x;
    int m0 = blockIdx.x * BM;
    int n0 = blockIdx.y * BN;
    int tx = tid & 15;
    int ty = tid >> 4;
    float acc[4][4] = {};
    int mA = tid >> 2;
    int kA = (tid & 3) * 4;
    int kB = tid >> 4;
    int nB = (tid & 15) * 4;
    for (int k0 = 0; k0 < K; k0 += BK) {
        int kk = k0 + kA;
        const float* Ap; int Asr; int Acc;
        if (kk < KA1) { Ap = A1; Asr = a1s; Acc = a1c + kk; }
        else          { Ap = A2; Asr = a2s; Acc = a2c + (kk - KA1); }
        int gm = m0 + mA;
        float4 av;
        if (gm < M) av = *(const float4*)&Ap[(size_t)gm * Asr + Acc];
        else        av = float4{0.f, 0.f, 0.f, 0.f};
        As[kA + 0][mA] = av.x; As[kA + 1][mA] = av.y;
        As[kA + 2][mA] = av.z; As[kA + 3][mA] = av.w;
        int kw = k0 + kB;
        const float* Wp; int kwl;
        if (kw < K / 2) { Wp = W1; kwl = kw; } else { Wp = W2; kwl = kw - K / 2; }
        float4 bv = *(const float4*)&Wp[(size_t)kwl * FOUT + n0 + nB];
        *(float4*)&Bs[kB][nB] = bv;
        __syncthreads();
        #pragma unroll
        for (int k = 0; k < BK; k++) {
            float a[4], b[4];
            *(float4*)a = *(const float4*)&As[k][ty * 4];
            *(float4*)b = *(const float4*)&Bs[k][tx * 4];
            #pragma unroll
            for (int i = 0; i < 4; i++)
                #pragma unroll
                for (int j = 0; j < 4; j++)
                    acc[i][j] += a[i] * b[j];
        }
        __syncthreads();
    }
    #pragma unroll
    for (int i = 0; i < 4; i++) {
        int gm = m0 + ty * 4 + i;
        if (gm >= M) continue;
        #pragma unroll
        for (int j = 0; j < 4; j++) {
            int gn = n0 + tx * 4 + j;
            float v = acc[i][j] + bias[gn];
            if (doRelu) v = (v > 0.f) ? v : 0.01f * v;
            D[(size_t)gm * dstr + dcol + gn] = v;
        }
    }
}

// ---------------------------------------------------------------- pooling init / finalize
__global__ __launch_bounds__(256)
void pool_init(float* __restrict__ pmax, float* __restrict__ psum, int G) {
    int t = blockIdx.x * 256 + threadIdx.x;
    if (t < G * 256) { pmax[t] = -INFINITY; psum[t] = 0.f; }
}

__global__ __launch_bounds__(256)
void pool_final(const float* __restrict__ pmax, const float* __restrict__ psum,
                const int* __restrict__ batch, float* __restrict__ pooled,
                int G, int n_nodes) {
    int t = blockIdx.x * 256 + threadIdx.x;
    if (t >= G * 256) return;
    int g = t >> 8, f = t & 255;
    int lo = 0, hi = n_nodes;
    while (lo < hi) { int mid = (lo + hi) >> 1; if (batch[mid] < g) lo = mid + 1; else hi = mid; }
    int start = lo;
    lo = start; hi = n_nodes;
    while (lo < hi) { int mid = (lo + hi) >> 1; if (batch[mid] < g + 1) lo = mid + 1; else hi = mid; }
    int end = lo;
    int c = end - start;
    float mx = pmax[t];
    if (c == 0) mx = 0.f;
    pooled[g * 512 + f] = mx;
    pooled[g * 512 + 256 + f] = psum[t] / (float)(c > 0 ? c : 1);
}

// ---------------------------------------------------------------- launcher
extern "C" void kernel_launch(void* const* d_in, const int* in_sizes, int n_in,
                              void* d_out, int out_size, void* d_ws, size_t ws_size,
                              hipStream_t stream) {
    const float* pos   = (const float*)d_in[0];
    const int*   eidx  = (const int*)d_in[1];
    const int*   batch = (const int*)d_in[2];
    const float* w_proj = (const float*)d_in[3];
    const float* b_proj = (const float*)d_in[4];
    const float* ws0 = (const float*)d_in[5];  const float* wn0 = (const float*)d_in[6];  const float* bb0 = (const float*)d_in[7];
    const float* ws1 = (const float*)d_in[8];  const float* wn1 = (const float*)d_in[9];  const float* bb1 = (const float*)d_in[10];
    const float* ws2 = (const float*)d_in[11]; const float* wn2 = (const float*)d_in[12]; const float* bb2 = (const float*)d_in[13];
    const float* ws3 = (const float*)d_in[14]; const float* wn3 = (const float*)d_in[15]; const float* bb3 = (const float*)d_in[16];
    const float* wd1 = (const float*)d_in[17]; const float* bd1 = (const float*)d_in[18];
    const float* wd2 = (const float*)d_in[19]; const float* bd2 = (const float*)d_in[20];

    int N = in_sizes[0] / 3;
    int E = in_sizes[1] / 2;
    int G = out_size / 256;
    const int* esrc_in = eidx;
    const int* edst_in = eidx + E;

    char* base = (char*)d_ws;
    size_t off = 0;
    auto alloc = [&](size_t bytes) -> void* {
        void* p = base + off;
        off = (off + bytes + 255) & ~(size_t)255;
        return p;
    };
    int*   cnt      = (int*)alloc((size_t)(N + 1) * 4);
    int*   rowstart = (int*)alloc((size_t)(N + 1) * 4);
    int*   cursor   = (int*)alloc((size_t)N * 4);
    int*   esrc     = (int*)alloc((size_t)E * 4);
    float* degf     = (float*)alloc((size_t)N * 4);
    int*   chunksum = (int*)alloc((size_t)256 * 4);
    unsigned short* XB0 = (unsigned short*)alloc((size_t)N * 128 * 2);  // [x | Sx]
    unsigned short* XB  = (unsigned short*)alloc((size_t)N * 512 * 2);  // [h0 h1 h2 | Sh0 Sh1 Sh2]
    float* pooled   = (float*)alloc((size_t)G * 512 * 4);
    float* hid      = (float*)alloc((size_t)G * 512 * 4);
    float* pmax     = (float*)alloc((size_t)G * 256 * 4);
    float* psum     = (float*)alloc((size_t)G * 256 * 4);
    unsigned short* WT0 = (unsigned short*)alloc((size_t)64 * 128 * 2);
    unsigned short* WT1 = (unsigned short*)alloc((size_t)64 * 128 * 2);
    unsigned short* WT2 = (unsigned short*)alloc((size_t)128 * 128 * 2);
    unsigned short* WT3 = (unsigned short*)alloc((size_t)256 * 512 * 2);

    // ---- weight prep (f16, transposed) ----
    wcvt<<<(2 * 64 * 64 + 255) / 256, 256, 0, stream>>>(ws0, wn0, 64, 64, WT0);
    wcvt<<<(2 * 64 * 64 + 255) / 256, 256, 0, stream>>>(ws1, wn1, 64, 64, WT1);
    wcvt<<<(2 * 64 * 128 + 255) / 256, 256, 0, stream>>>(ws2, wn2, 64, 128, WT2);
    wcvt<<<(2 * 256 * 256 + 255) / 256, 256, 0, stream>>>(ws3, wn3, 256, 256, WT3);

    // ---- CSR build ----
    (void)hipMemsetAsync(cnt, 0, (size_t)(N + 1) * 4, stream);
    hist_k<<<(E + 255) / 256, 256, 0, stream>>>(edst_in, cnt, E);
    int PB = (N + SCHUNK - 1) / SCHUNK;
    scan_part<<<PB, 256, 0, stream>>>(cnt, rowstart, chunksum, N);
    scan_tops<<<1, 64, 0, stream>>>(chunksum, rowstart, PB, N);
    scan_fix<<<PB, 256, 0, stream>>>(cnt, rowstart, chunksum, cursor, degf, N);
    scatter_k<<<(E + 255) / 256, 256, 0, stream>>>(esrc_in, edst_in, cursor, esrc, E);

    // ---- projection ----
    proj_k<<<(N * 64 + 255) / 256, 256, 0, stream>>>(pos, w_proj, b_proj, XB0, N);

    int ab  = (N + 3) / 4;
    int mb2 = (N + 127) / 128;

    // layer 0: agg(x) -> XB0 cols 64..128; gemm -> h0 (XB cols 0..64)
    agg_f16<64><<<ab, 256, 0, stream>>>(XB0, 128, XB0 + 64, 128, rowstart, esrc, degf, N);
    gemm_rb<128, 64, 0><<<mb2, 256, 0, stream>>>(
        XB0, 128, 128, 0, 0, WT0, bb0, XB, 512, 0, nullptr, nullptr, nullptr, N);

    // layer 1: agg(h0) -> XB cols 256..320; gemm -> h1 (XB cols 64..128)
    agg_f16<64><<<ab, 256, 0, stream>>>(XB, 512, XB + 256, 512, rowstart, esrc, degf, N);
    gemm_rb<128, 64, 0><<<mb2, 256, 0, stream>>>(
        XB, 512, 64, 0, 256, WT1, bb1, XB, 512, 64, nullptr, nullptr, nullptr, N);

    // layer 2: agg(h1) -> XB cols 320..384; gemm -> h2 (XB cols 128..256)
    agg_f16<64><<<ab, 256, 0, stream>>>(XB + 64, 512, XB + 320, 512, rowstart, esrc, degf, N);
    gemm_rb<128, 128, 0><<<mb2, 256, 0, stream>>>(
        XB, 512, 64, 64, 320, WT2, bb2, XB, 512, 128, nullptr, nullptr, nullptr, N);

    // layer 3: agg(h2) -> XB cols 384..512; K=512 gemm with fused pooling epilogue
    agg_f16<128><<<ab, 256, 0, stream>>>(XB + 128, 512, XB + 384, 512, rowstart, esrc, degf, N);
    pool_init<<<(G * 256 + 255) / 256, 256, 0, stream>>>(pmax, psum, G);
    gemm_rb<512, 128, 1><<<dim3(mb2, 2), 256, 0, stream>>>(
        XB, 512, 512, 0, 0, WT3, bb3, nullptr, 0, 0, pmax, psum, batch, N);
    pool_final<<<(G * 256 + 255) / 256, 256, 0, stream>>>(pmax, psum, batch, pooled, G, N);

    // ---- dense head (fp32) ----
    gemm_lrelu<512, 512><<<dim3((G + 63) / 64, 8), 256, 0, stream>>>(
        pooled, 512, 0, 512, pooled, 512, 0, wd1, wd1 + 256 * 512, bd1, hid, 512, 0, G, 1);
    gemm_lrelu<512, 256><<<dim3((G + 63) / 64, 4), 256, 0, stream>>>(
        hid, 512, 0, 512, hid, 512, 0, wd2, wd2 + 256 * 256, bd2, (float*)d_out, 256, 0, G, 0);
}